// Round 1
// baseline (5877.925 us; speedup 1.0000x reference)
//
#include <hip/hip_runtime.h>
#include <hip/hip_bf16.h>

#define FDIM 256
#define OUTC 128

// ---------------------------------------------------------------------------
// Scatter-add: agg[dst] += x[src] for each edge. One wave (64 lanes) per edge;
// each lane handles a float4 (64*4 = 256 features).
// ---------------------------------------------------------------------------
__global__ __launch_bounds__(256)
void scatter_add_kernel(const float* __restrict__ x,
                        const int* __restrict__ src,
                        const int* __restrict__ dst,
                        float* __restrict__ agg, int E) {
    int gw   = (int)((blockIdx.x * blockDim.x + threadIdx.x) >> 6);
    int lane = threadIdx.x & 63;
    if (gw >= E) return;
    int s = src[gw];
    int d = dst[gw];
    float4 v = ((const float4*)(x + (size_t)s * FDIM))[lane];
    float* a = agg + (size_t)d * FDIM + lane * 4;
    atomicAdd(a + 0, v.x);
    atomicAdd(a + 1, v.y);
    atomicAdd(a + 2, v.z);
    atomicAdd(a + 3, v.w);
}

// ---------------------------------------------------------------------------
// Tiled fp32 GEMM: C[M,N] = op(A) @ B[K,N] + bias, optional ReLU.
// op(A) = (1+eps)*A + agg  when FUSE_AGG, else A.
// BM=64, BN=64, BK=16, 256 threads, 4x4 micro-tile per thread.
// N and K must be multiples of 64/16 (true here: N in {256,128}, K=256).
// ---------------------------------------------------------------------------
template<bool RELU, bool FUSE_AGG>
__global__ __launch_bounds__(256)
void gemm_kernel(const float* __restrict__ A,
                 const float* __restrict__ agg,
                 const float* __restrict__ epsp,
                 const float* __restrict__ B,
                 const float* __restrict__ bias,
                 float* __restrict__ C,
                 int M, int N, int K) {
    const int BM = 64, BN = 64, BK = 16;
    __shared__ float As[BK][BM];
    __shared__ float Bs[BK][BN];

    int tid = threadIdx.x;
    int tx  = tid & 15;   // col group (4 cols each)
    int ty  = tid >> 4;   // row group (4 rows each)
    int row0 = blockIdx.y * BM;
    int col0 = blockIdx.x * BN;

    float scale = 0.0f;
    if (FUSE_AGG) scale = 1.0f + *epsp;

    // A-tile load mapping: 64 rows x 16 k, one float4 per thread along K
    int lr = tid >> 2;          // 0..63 (row in tile)
    int lc = (tid & 3) * 4;     // 0,4,8,12 (k offset)
    // B-tile load mapping: 16 k-rows x 64 cols, one float4 per thread along N
    int br = tid >> 4;          // 0..15 (k row)
    int bc = (tid & 15) * 4;    // 0..60 (col offset)

    float acc[4][4] = {};

    for (int kb = 0; kb < K; kb += BK) {
        int arow = row0 + lr;
        float4 av = make_float4(0.f, 0.f, 0.f, 0.f);
        if (arow < M) {
            av = *(const float4*)(A + (size_t)arow * K + kb + lc);
            if (FUSE_AGG) {
                float4 gv = *(const float4*)(agg + (size_t)arow * K + kb + lc);
                av.x = scale * av.x + gv.x;
                av.y = scale * av.y + gv.y;
                av.z = scale * av.z + gv.z;
                av.w = scale * av.w + gv.w;
            }
        }
        As[lc + 0][lr] = av.x;
        As[lc + 1][lr] = av.y;
        As[lc + 2][lr] = av.z;
        As[lc + 3][lr] = av.w;

        *(float4*)&Bs[br][bc] =
            *(const float4*)(B + (size_t)(kb + br) * N + col0 + bc);

        __syncthreads();

        #pragma unroll
        for (int k = 0; k < BK; ++k) {
            float4 a = *(const float4*)&As[k][ty * 4];
            float4 b = *(const float4*)&Bs[k][tx * 4];
            acc[0][0] += a.x * b.x; acc[0][1] += a.x * b.y;
            acc[0][2] += a.x * b.z; acc[0][3] += a.x * b.w;
            acc[1][0] += a.y * b.x; acc[1][1] += a.y * b.y;
            acc[1][2] += a.y * b.z; acc[1][3] += a.y * b.w;
            acc[2][0] += a.z * b.x; acc[2][1] += a.z * b.y;
            acc[2][2] += a.z * b.z; acc[2][3] += a.z * b.w;
            acc[3][0] += a.w * b.x; acc[3][1] += a.w * b.y;
            acc[3][2] += a.w * b.z; acc[3][3] += a.w * b.w;
        }
        __syncthreads();
    }

    float4 bv = *(const float4*)(bias + col0 + tx * 4);
    #pragma unroll
    for (int i = 0; i < 4; ++i) {
        int r = row0 + ty * 4 + i;
        if (r < M) {
            float4 o;
            o.x = acc[i][0] + bv.x;
            o.y = acc[i][1] + bv.y;
            o.z = acc[i][2] + bv.z;
            o.w = acc[i][3] + bv.w;
            if (RELU) {
                o.x = fmaxf(o.x, 0.f);
                o.y = fmaxf(o.y, 0.f);
                o.z = fmaxf(o.z, 0.f);
                o.w = fmaxf(o.w, 0.f);
            }
            *(float4*)(C + (size_t)r * N + col0 + tx * 4) = o;
        }
    }
}

// ---------------------------------------------------------------------------
// In-place log_softmax over rows of 128 floats. One wave per row.
// ---------------------------------------------------------------------------
__global__ __launch_bounds__(256)
void log_softmax_kernel(float* __restrict__ out, int M) {
    int gw   = (int)((blockIdx.x * blockDim.x + threadIdx.x) >> 6);
    int lane = threadIdx.x & 63;
    if (gw >= M) return;
    float* row = out + (size_t)gw * OUTC;
    float2 v = *(const float2*)(row + lane * 2);
    float m = fmaxf(v.x, v.y);
    #pragma unroll
    for (int off = 32; off; off >>= 1) m = fmaxf(m, __shfl_xor(m, off));
    float s = __expf(v.x - m) + __expf(v.y - m);
    #pragma unroll
    for (int off = 32; off; off >>= 1) s += __shfl_xor(s, off);
    float lse = m + __logf(s);
    float2 o = make_float2(v.x - lse, v.y - lse);
    *(float2*)(row + lane * 2) = o;
}

// ---------------------------------------------------------------------------
extern "C" void kernel_launch(void* const* d_in, const int* in_sizes, int n_in,
                              void* d_out, int out_size, void* d_ws, size_t ws_size,
                              hipStream_t stream) {
    const float* x    = (const float*)d_in[0];
    const int*   ei   = (const int*)d_in[1];   // [2, E] int32
    const float* eps0 = (const float*)d_in[2];
    const float* W1_0 = (const float*)d_in[3];
    const float* b1_0 = (const float*)d_in[4];
    const float* W2_0 = (const float*)d_in[5];
    const float* b2_0 = (const float*)d_in[6];
    const float* eps1 = (const float*)d_in[7];
    const float* W1_1 = (const float*)d_in[8];
    const float* b1_1 = (const float*)d_in[9];
    const float* W2_1 = (const float*)d_in[10];
    const float* b2_1 = (const float*)d_in[11];
    float* out = (float*)d_out;

    const int N = in_sizes[0] / FDIM;      // 50000
    const int E = in_sizes[1] / 2;         // 800000
    const int* src = ei;
    const int* dst = ei + E;

    size_t buf_elems = (size_t)N * FDIM;
    float* agg = (float*)d_ws;
    float* h1  = agg + buf_elems;
    float* h2  = h1 + buf_elems;

    const int BM = 64, BN = 64;
    dim3 gemm_block(256);
    dim3 gemm_grid_h((FDIM + BN - 1) / BN, (N + BM - 1) / BM);   // 4 x 782
    dim3 gemm_grid_o((OUTC + BN - 1) / BN, (N + BM - 1) / BM);   // 2 x 782

    int scatter_blocks = (E + 3) / 4;       // 4 edges (waves) per 256-thr block

    // ---- layer 0 ----
    hipMemsetAsync(agg, 0, buf_elems * sizeof(float), stream);
    scatter_add_kernel<<<scatter_blocks, 256, 0, stream>>>(x, src, dst, agg, E);
    gemm_kernel<true, true><<<gemm_grid_h, gemm_block, 0, stream>>>(
        x, agg, eps0, W1_0, b1_0, h1, N, FDIM, FDIM);
    gemm_kernel<true, false><<<gemm_grid_h, gemm_block, 0, stream>>>(
        h1, nullptr, nullptr, W2_0, b2_0, h2, N, FDIM, FDIM);

    // ---- layer 1 ----
    hipMemsetAsync(agg, 0, buf_elems * sizeof(float), stream);
    scatter_add_kernel<<<scatter_blocks, 256, 0, stream>>>(h2, src, dst, agg, E);
    gemm_kernel<true, true><<<gemm_grid_h, gemm_block, 0, stream>>>(
        h2, agg, eps1, W1_1, b1_1, h1, N, FDIM, FDIM);
    gemm_kernel<false, false><<<gemm_grid_o, gemm_block, 0, stream>>>(
        h1, nullptr, nullptr, W2_1, b2_1, out, N, OUTC, FDIM);

    // ---- log_softmax ----
    int ls_blocks = (N + 3) / 4;
    log_softmax_kernel<<<ls_blocks, 256, 0, stream>>>(out, N);
}

// Round 2
// 914.153 us; speedup vs baseline: 6.4299x; 6.4299x over previous
//
#include <hip/hip_runtime.h>
#include <hip/hip_bf16.h>

#define FDIM 256
#define OUTC 128

// ===========================================================================
// CSR build: histogram -> exclusive scan -> binning
// ===========================================================================
__global__ __launch_bounds__(256)
void histogram_kernel(const int* __restrict__ dst, int* __restrict__ counts, int E) {
    int i = blockIdx.x * blockDim.x + threadIdx.x;
    if (i < E) atomicAdd(&counts[dst[i]], 1);
}

// One-block exclusive scan over N counts (N ~ 50000). 1024 threads.
__global__ __launch_bounds__(1024)
void scan_kernel(const int* __restrict__ counts, int* __restrict__ offsets, int N) {
    __shared__ int sums[1024];
    int tid = threadIdx.x;
    int chunk = (N + 1023) >> 10;
    int begin = tid * chunk;
    int end = begin + chunk; if (end > N) end = N;
    int s = 0;
    for (int i = begin; i < end; ++i) s += counts[i];
    sums[tid] = s;
    __syncthreads();
    // inclusive Hillis-Steele scan over thread sums
    for (int off = 1; off < 1024; off <<= 1) {
        int t = (tid >= off) ? sums[tid - off] : 0;
        __syncthreads();
        sums[tid] += t;
        __syncthreads();
    }
    int run = sums[tid] - s;   // exclusive prefix for this thread's chunk
    for (int i = begin; i < end; ++i) {
        offsets[i] = run;
        run += counts[i];
    }
}

__global__ __launch_bounds__(256)
void binning_kernel(const int* __restrict__ src, const int* __restrict__ dst,
                    const int* __restrict__ offsets, int* __restrict__ cursor,
                    int* __restrict__ esrc, int E) {
    int i = blockIdx.x * blockDim.x + threadIdx.x;
    if (i < E) {
        int d = dst[i];
        int pos = offsets[d] + atomicAdd(&cursor[d], 1);
        esrc[pos] = src[i];
    }
}

// ===========================================================================
// Gather-aggregate, fused with (1+eps)*x: out[n] = (1+eps)*x[n] + sum x[src]
// One wave (64 lanes) per node; each lane owns a float4 (256 feats).
// ===========================================================================
__global__ __launch_bounds__(256)
void gather_kernel(const float* __restrict__ x, const int* __restrict__ esrc,
                   const int* __restrict__ offsets, const int* __restrict__ counts,
                   const float* __restrict__ epsp, float* __restrict__ out, int N) {
    int node = (int)((blockIdx.x * blockDim.x + threadIdx.x) >> 6);
    int lane = threadIdx.x & 63;
    if (node >= N) return;
    float scale = 1.0f + *epsp;
    int beg = offsets[node];
    int cnt = counts[node];
    float4 xv = ((const float4*)(x + (size_t)node * FDIM))[lane];
    float4 acc = make_float4(scale * xv.x, scale * xv.y, scale * xv.z, scale * xv.w);
    int e = 0;
    for (; e + 1 < cnt; e += 2) {
        int s0 = esrc[beg + e];
        int s1 = esrc[beg + e + 1];
        float4 v0 = ((const float4*)(x + (size_t)s0 * FDIM))[lane];
        float4 v1 = ((const float4*)(x + (size_t)s1 * FDIM))[lane];
        acc.x += v0.x + v1.x; acc.y += v0.y + v1.y;
        acc.z += v0.z + v1.z; acc.w += v0.w + v1.w;
    }
    if (e < cnt) {
        int s0 = esrc[beg + e];
        float4 v0 = ((const float4*)(x + (size_t)s0 * FDIM))[lane];
        acc.x += v0.x; acc.y += v0.y; acc.z += v0.z; acc.w += v0.w;
    }
    ((float4*)(out + (size_t)node * FDIM))[lane] = acc;
}

// ===========================================================================
// Fallback scatter-add (used only if ws_size can't fit CSR arrays)
// ===========================================================================
__global__ __launch_bounds__(256)
void scatter_add_kernel(const float* __restrict__ x,
                        const int* __restrict__ src,
                        const int* __restrict__ dst,
                        float* __restrict__ agg, int E) {
    int gw   = (int)((blockIdx.x * blockDim.x + threadIdx.x) >> 6);
    int lane = threadIdx.x & 63;
    if (gw >= E) return;
    int s = src[gw];
    int d = dst[gw];
    float4 v = ((const float4*)(x + (size_t)s * FDIM))[lane];
    float* a = agg + (size_t)d * FDIM + lane * 4;
    atomicAdd(a + 0, v.x);
    atomicAdd(a + 1, v.y);
    atomicAdd(a + 2, v.z);
    atomicAdd(a + 3, v.w);
}

// ===========================================================================
// Tiled fp32 GEMM: C[M,N] = op(A) @ B[K,N] + bias, optional ReLU.
// op(A) = (1+eps)*A + agg  when FUSE_AGG (fallback path only).
// ===========================================================================
template<bool RELU, bool FUSE_AGG>
__global__ __launch_bounds__(256)
void gemm_kernel(const float* __restrict__ A,
                 const float* __restrict__ agg,
                 const float* __restrict__ epsp,
                 const float* __restrict__ B,
                 const float* __restrict__ bias,
                 float* __restrict__ C,
                 int M, int N, int K) {
    const int BM = 64, BN = 64, BK = 16;
    __shared__ float As[BK][BM];
    __shared__ float Bs[BK][BN];

    int tid = threadIdx.x;
    int tx  = tid & 15;
    int ty  = tid >> 4;
    int row0 = blockIdx.y * BM;
    int col0 = blockIdx.x * BN;

    float scale = 0.0f;
    if (FUSE_AGG) scale = 1.0f + *epsp;

    int lr = tid >> 2;
    int lc = (tid & 3) * 4;
    int br = tid >> 4;
    int bc = (tid & 15) * 4;

    float acc[4][4] = {};

    for (int kb = 0; kb < K; kb += BK) {
        int arow = row0 + lr;
        float4 av = make_float4(0.f, 0.f, 0.f, 0.f);
        if (arow < M) {
            av = *(const float4*)(A + (size_t)arow * K + kb + lc);
            if (FUSE_AGG) {
                float4 gv = *(const float4*)(agg + (size_t)arow * K + kb + lc);
                av.x = scale * av.x + gv.x;
                av.y = scale * av.y + gv.y;
                av.z = scale * av.z + gv.z;
                av.w = scale * av.w + gv.w;
            }
        }
        As[lc + 0][lr] = av.x;
        As[lc + 1][lr] = av.y;
        As[lc + 2][lr] = av.z;
        As[lc + 3][lr] = av.w;

        *(float4*)&Bs[br][bc] =
            *(const float4*)(B + (size_t)(kb + br) * N + col0 + bc);

        __syncthreads();

        #pragma unroll
        for (int k = 0; k < BK; ++k) {
            float4 a = *(const float4*)&As[k][ty * 4];
            float4 b = *(const float4*)&Bs[k][tx * 4];
            acc[0][0] += a.x * b.x; acc[0][1] += a.x * b.y;
            acc[0][2] += a.x * b.z; acc[0][3] += a.x * b.w;
            acc[1][0] += a.y * b.x; acc[1][1] += a.y * b.y;
            acc[1][2] += a.y * b.z; acc[1][3] += a.y * b.w;
            acc[2][0] += a.z * b.x; acc[2][1] += a.z * b.y;
            acc[2][2] += a.z * b.z; acc[2][3] += a.z * b.w;
            acc[3][0] += a.w * b.x; acc[3][1] += a.w * b.y;
            acc[3][2] += a.w * b.z; acc[3][3] += a.w * b.w;
        }
        __syncthreads();
    }

    float4 bv = *(const float4*)(bias + col0 + tx * 4);
    #pragma unroll
    for (int i = 0; i < 4; ++i) {
        int r = row0 + ty * 4 + i;
        if (r < M) {
            float4 o;
            o.x = acc[i][0] + bv.x;
            o.y = acc[i][1] + bv.y;
            o.z = acc[i][2] + bv.z;
            o.w = acc[i][3] + bv.w;
            if (RELU) {
                o.x = fmaxf(o.x, 0.f);
                o.y = fmaxf(o.y, 0.f);
                o.z = fmaxf(o.z, 0.f);
                o.w = fmaxf(o.w, 0.f);
            }
            *(float4*)(C + (size_t)r * N + col0 + tx * 4) = o;
        }
    }
}

// ===========================================================================
// In-place log_softmax over rows of 128 floats. One wave per row.
// ===========================================================================
__global__ __launch_bounds__(256)
void log_softmax_kernel(float* __restrict__ out, int M) {
    int gw   = (int)((blockIdx.x * blockDim.x + threadIdx.x) >> 6);
    int lane = threadIdx.x & 63;
    if (gw >= M) return;
    float* row = out + (size_t)gw * OUTC;
    float2 v = *(const float2*)(row + lane * 2);
    float m = fmaxf(v.x, v.y);
    #pragma unroll
    for (int off = 32; off; off >>= 1) m = fmaxf(m, __shfl_xor(m, off));
    float s = __expf(v.x - m) + __expf(v.y - m);
    #pragma unroll
    for (int off = 32; off; off >>= 1) s += __shfl_xor(s, off);
    float lse = m + __logf(s);
    float2 o = make_float2(v.x - lse, v.y - lse);
    *(float2*)(row + lane * 2) = o;
}

// ===========================================================================
extern "C" void kernel_launch(void* const* d_in, const int* in_sizes, int n_in,
                              void* d_out, int out_size, void* d_ws, size_t ws_size,
                              hipStream_t stream) {
    const float* x    = (const float*)d_in[0];
    const int*   ei   = (const int*)d_in[1];
    const float* eps0 = (const float*)d_in[2];
    const float* W1_0 = (const float*)d_in[3];
    const float* b1_0 = (const float*)d_in[4];
    const float* W2_0 = (const float*)d_in[5];
    const float* b2_0 = (const float*)d_in[6];
    const float* eps1 = (const float*)d_in[7];
    const float* W1_1 = (const float*)d_in[8];
    const float* b1_1 = (const float*)d_in[9];
    const float* W2_1 = (const float*)d_in[10];
    const float* b2_1 = (const float*)d_in[11];
    float* out = (float*)d_out;

    const int N = in_sizes[0] / FDIM;      // 50000
    const int E = in_sizes[1] / 2;         // 800000
    const int* src = ei;
    const int* dst = ei + E;

    size_t buf_elems = (size_t)N * FDIM;
    float* agg = (float*)d_ws;
    float* h1  = agg + buf_elems;
    float* h2  = h1 + buf_elems;

    // CSR arrays appended after the three float buffers
    int* counts  = (int*)(h2 + buf_elems);
    int* offsets = counts + N;
    int* cursor  = offsets + N;
    int* esrc    = cursor + N;
    size_t need = 3 * buf_elems * sizeof(float) + ((size_t)3 * N + E) * sizeof(int);
    bool use_csr = (ws_size >= need);

    const int BM = 64, BN = 64;
    dim3 gemm_block(256);
    dim3 gemm_grid_h((FDIM + BN - 1) / BN, (N + BM - 1) / BM);
    dim3 gemm_grid_o((OUTC + BN - 1) / BN, (N + BM - 1) / BM);

    int eb = (E + 255) / 256;            // 1 thread per edge
    int gather_blocks = (N + 3) / 4;     // 4 waves (nodes) per block

    if (use_csr) {
        // ---- build CSR once (shared by both layers) ----
        hipMemsetAsync(counts, 0, (size_t)N * sizeof(int), stream);
        hipMemsetAsync(cursor, 0, (size_t)N * sizeof(int), stream);
        histogram_kernel<<<eb, 256, 0, stream>>>(dst, counts, E);
        scan_kernel<<<1, 1024, 0, stream>>>(counts, offsets, N);
        binning_kernel<<<eb, 256, 0, stream>>>(src, dst, offsets, cursor, esrc, E);

        // ---- layer 0 ----
        gather_kernel<<<gather_blocks, 256, 0, stream>>>(x, esrc, offsets, counts, eps0, agg, N);
        gemm_kernel<true, false><<<gemm_grid_h, gemm_block, 0, stream>>>(
            agg, nullptr, nullptr, W1_0, b1_0, h1, N, FDIM, FDIM);
        gemm_kernel<true, false><<<gemm_grid_h, gemm_block, 0, stream>>>(
            h1, nullptr, nullptr, W2_0, b2_0, h2, N, FDIM, FDIM);

        // ---- layer 1 ----
        gather_kernel<<<gather_blocks, 256, 0, stream>>>(h2, esrc, offsets, counts, eps1, agg, N);
        gemm_kernel<true, false><<<gemm_grid_h, gemm_block, 0, stream>>>(
            agg, nullptr, nullptr, W1_1, b1_1, h1, N, FDIM, FDIM);
        gemm_kernel<false, false><<<gemm_grid_o, gemm_block, 0, stream>>>(
            h1, nullptr, nullptr, W2_1, b2_1, out, N, OUTC, FDIM);
    } else {
        // ---- fallback: atomic scatter path (round-0 behavior) ----
        int scatter_blocks = (E + 3) / 4;
        hipMemsetAsync(agg, 0, buf_elems * sizeof(float), stream);
        scatter_add_kernel<<<scatter_blocks, 256, 0, stream>>>(x, src, dst, agg, E);
        gemm_kernel<true, true><<<gemm_grid_h, gemm_block, 0, stream>>>(
            x, agg, eps0, W1_0, b1_0, h1, N, FDIM, FDIM);
        gemm_kernel<true, false><<<gemm_grid_h, gemm_block, 0, stream>>>(
            h1, nullptr, nullptr, W2_0, b2_0, h2, N, FDIM, FDIM);
        hipMemsetAsync(agg, 0, buf_elems * sizeof(float), stream);
        scatter_add_kernel<<<scatter_blocks, 256, 0, stream>>>(h2, src, dst, agg, E);
        gemm_kernel<true, true><<<gemm_grid_h, gemm_block, 0, stream>>>(
            h2, agg, eps1, W1_1, b1_1, h1, N, FDIM, FDIM);
        gemm_kernel<false, false><<<gemm_grid_o, gemm_block, 0, stream>>>(
            h1, nullptr, nullptr, W2_1, b2_1, out, N, OUTC, FDIM);
    }

    // ---- log_softmax ----
    int ls_blocks = (N + 3) / 4;
    log_softmax_kernel<<<ls_blocks, 256, 0, stream>>>(out, N);
}

// Round 3
// 616.275 us; speedup vs baseline: 9.5378x; 1.4834x over previous
//
#include <hip/hip_runtime.h>
#include <hip/hip_bf16.h>

#define FDIM 256
#define OUTC 128

typedef float floatx4 __attribute__((ext_vector_type(4)));
typedef __bf16 bf16x8 __attribute__((ext_vector_type(8)));

__device__ __forceinline__ unsigned short f2bf(float f) {
    union { float f; unsigned u; } v; v.f = f;
    unsigned r = v.u + 0x7FFF + ((v.u >> 16) & 1);   // RNE
    return (unsigned short)(r >> 16);
}
__device__ __forceinline__ float bf2f(unsigned short b) {
    union { unsigned u; float f; } v; v.u = ((unsigned)b) << 16;
    return v.f;
}

// ===========================================================================
// CSR build: histogram -> exclusive scan -> binning
// ===========================================================================
__global__ __launch_bounds__(256)
void histogram_kernel(const int* __restrict__ dst, int* __restrict__ counts, int E) {
    int i = blockIdx.x * blockDim.x + threadIdx.x;
    if (i < E) atomicAdd(&counts[dst[i]], 1);
}

__global__ __launch_bounds__(1024)
void scan_kernel(const int* __restrict__ counts, int* __restrict__ offsets, int N) {
    __shared__ int sums[1024];
    int tid = threadIdx.x;
    int chunk = (N + 1023) >> 10;
    int begin = tid * chunk;
    int end = begin + chunk; if (end > N) end = N;
    int s = 0;
    for (int i = begin; i < end; ++i) s += counts[i];
    sums[tid] = s;
    __syncthreads();
    for (int off = 1; off < 1024; off <<= 1) {
        int t = (tid >= off) ? sums[tid - off] : 0;
        __syncthreads();
        sums[tid] += t;
        __syncthreads();
    }
    int run = sums[tid] - s;
    for (int i = begin; i < end; ++i) {
        offsets[i] = run;
        run += counts[i];
    }
}

__global__ __launch_bounds__(256)
void binning_kernel(const int* __restrict__ src, const int* __restrict__ dst,
                    const int* __restrict__ offsets, int* __restrict__ cursor,
                    int* __restrict__ esrc, int E) {
    int i = blockIdx.x * blockDim.x + threadIdx.x;
    if (i < E) {
        int d = dst[i];
        int pos = offsets[d] + atomicAdd(&cursor[d], 1);
        esrc[pos] = src[i];
    }
}

// ===========================================================================
// Weight convert + transpose: W[K,N] fp32 -> WT[N,K] bf16
// ===========================================================================
__global__ __launch_bounds__(256)
void convert_wt_kernel(const float* __restrict__ W, unsigned short* __restrict__ WT,
                       int K, int N) {
    int idx = blockIdx.x * blockDim.x + threadIdx.x;   // over N*K, k fastest
    if (idx < N * K) {
        int n = idx / K;
        int k = idx - n * K;
        WT[idx] = f2bf(W[(size_t)k * N + n]);
    }
}

// ===========================================================================
// Gather-aggregate (fp32 input -> bf16 out): out[n] = (1+eps)*x[n] + sum x[src]
// One wave per node; lane owns 4 consecutive features.
// ===========================================================================
__global__ __launch_bounds__(256)
void gather_f32_kernel(const float* __restrict__ x, const int* __restrict__ esrc,
                       const int* __restrict__ offsets, const int* __restrict__ counts,
                       const float* __restrict__ epsp, unsigned short* __restrict__ out,
                       int N) {
    int node = (int)((blockIdx.x * blockDim.x + threadIdx.x) >> 6);
    int lane = threadIdx.x & 63;
    if (node >= N) return;
    float scale = 1.0f + *epsp;
    int beg = offsets[node];
    int cnt = counts[node];
    float4 xv = ((const float4*)(x + (size_t)node * FDIM))[lane];
    float4 acc = make_float4(scale * xv.x, scale * xv.y, scale * xv.z, scale * xv.w);
    int e = 0;
    for (; e + 1 < cnt; e += 2) {
        int s0 = esrc[beg + e];
        int s1 = esrc[beg + e + 1];
        float4 v0 = ((const float4*)(x + (size_t)s0 * FDIM))[lane];
        float4 v1 = ((const float4*)(x + (size_t)s1 * FDIM))[lane];
        acc.x += v0.x + v1.x; acc.y += v0.y + v1.y;
        acc.z += v0.z + v1.z; acc.w += v0.w + v1.w;
    }
    if (e < cnt) {
        int s0 = esrc[beg + e];
        float4 v0 = ((const float4*)(x + (size_t)s0 * FDIM))[lane];
        acc.x += v0.x; acc.y += v0.y; acc.z += v0.z; acc.w += v0.w;
    }
    ushort4 o;
    o.x = f2bf(acc.x); o.y = f2bf(acc.y); o.z = f2bf(acc.z); o.w = f2bf(acc.w);
    ((ushort4*)(out + (size_t)node * FDIM))[lane] = o;
}

// Gather-aggregate (bf16 input -> bf16 out), fp32 accumulation.
__global__ __launch_bounds__(256)
void gather_bf16_kernel(const unsigned short* __restrict__ x, const int* __restrict__ esrc,
                        const int* __restrict__ offsets, const int* __restrict__ counts,
                        const float* __restrict__ epsp, unsigned short* __restrict__ out,
                        int N) {
    int node = (int)((blockIdx.x * blockDim.x + threadIdx.x) >> 6);
    int lane = threadIdx.x & 63;
    if (node >= N) return;
    float scale = 1.0f + *epsp;
    int beg = offsets[node];
    int cnt = counts[node];
    ushort4 xv = ((const ushort4*)(x + (size_t)node * FDIM))[lane];
    float4 acc = make_float4(scale * bf2f(xv.x), scale * bf2f(xv.y),
                             scale * bf2f(xv.z), scale * bf2f(xv.w));
    for (int e = 0; e < cnt; ++e) {
        int s0 = esrc[beg + e];
        ushort4 v = ((const ushort4*)(x + (size_t)s0 * FDIM))[lane];
        acc.x += bf2f(v.x); acc.y += bf2f(v.y);
        acc.z += bf2f(v.z); acc.w += bf2f(v.w);
    }
    ushort4 o;
    o.x = f2bf(acc.x); o.y = f2bf(acc.y); o.z = f2bf(acc.z); o.w = f2bf(acc.w);
    ((ushort4*)(out + (size_t)node * FDIM))[lane] = o;
}

// ===========================================================================
// bf16 MFMA GEMM: C[M,N] = A[M,K] @ WT[N,K]^T + bias, optional ReLU.
// BM=128, BN=128, BK=64; 256 threads = 4 waves (2x2), each wave 64x64 via
// 4x4 grid of mfma_f32_16x16x32_bf16. LDS stride padded to 72 (2-way = free).
// ===========================================================================
#define BM 128
#define BN 128
#define BK 64
#define LDK 72

template<bool RELU, bool OUT_BF16>
__global__ __launch_bounds__(256)
void gemm_bf16_kernel(const unsigned short* __restrict__ A,   // [M,K] bf16
                      const unsigned short* __restrict__ WT,  // [N,K] bf16
                      const float* __restrict__ bias,         // [N]
                      void* __restrict__ C,                   // [M,N]
                      int M, int N, int K) {
    __shared__ unsigned short As[BM * LDK];
    __shared__ unsigned short Bs[BN * LDK];

    int tid  = threadIdx.x;
    int wave = tid >> 6;
    int lane = tid & 63;
    int wr   = wave >> 1;     // 0..1
    int wc   = wave & 1;      // 0..1
    int l15  = lane & 15;
    int quad = lane >> 4;     // 0..3

    int row0 = blockIdx.y * BM;
    int col0 = blockIdx.x * BN;

    floatx4 zero = {0.f, 0.f, 0.f, 0.f};
    floatx4 acc[4][4];
    #pragma unroll
    for (int i = 0; i < 4; ++i)
        #pragma unroll
        for (int j = 0; j < 4; ++j) acc[i][j] = zero;

    // staging mapping: 1024 chunks of 16B (8 bf16); chunk f -> row f>>3, ck f&7
    int srow = tid >> 3;        // base row for this thread (0..31), step 32
    int sck  = tid & 7;         // 16B chunk within row

    for (int kb = 0; kb < K; kb += BK) {
        #pragma unroll
        for (int i = 0; i < 4; ++i) {
            int r = srow + i * 32;
            int gr = row0 + r;
            uint4 v = make_uint4(0u, 0u, 0u, 0u);
            if (gr < M) v = *(const uint4*)(A + (size_t)gr * K + kb + sck * 8);
            *(uint4*)(As + r * LDK + sck * 8) = v;
        }
        #pragma unroll
        for (int i = 0; i < 4; ++i) {
            int r = srow + i * 32;
            uint4 v = *(const uint4*)(WT + (size_t)(col0 + r) * K + kb + sck * 8);
            *(uint4*)(Bs + r * LDK + sck * 8) = v;
        }
        __syncthreads();

        #pragma unroll
        for (int ks = 0; ks < 2; ++ks) {
            bf16x8 af[4], bf[4];
            #pragma unroll
            for (int i = 0; i < 4; ++i)
                af[i] = *(const bf16x8*)(As + (wr * 64 + i * 16 + l15) * LDK + ks * 32 + quad * 8);
            #pragma unroll
            for (int j = 0; j < 4; ++j)
                bf[j] = *(const bf16x8*)(Bs + (wc * 64 + j * 16 + l15) * LDK + ks * 32 + quad * 8);
            #pragma unroll
            for (int i = 0; i < 4; ++i)
                #pragma unroll
                for (int j = 0; j < 4; ++j)
                    acc[i][j] = __builtin_amdgcn_mfma_f32_16x16x32_bf16(
                        af[i], bf[j], acc[i][j], 0, 0, 0);
        }
        __syncthreads();
    }

    // epilogue: C/D layout col=lane&15, row=quad*4+reg
    #pragma unroll
    for (int j = 0; j < 4; ++j) {
        int col = col0 + wc * 64 + j * 16 + l15;
        float bv = bias[col];
        #pragma unroll
        for (int i = 0; i < 4; ++i) {
            int rbase = row0 + wr * 64 + i * 16 + quad * 4;
            #pragma unroll
            for (int r = 0; r < 4; ++r) {
                int row = rbase + r;
                if (row < M) {
                    float v = acc[i][j][r] + bv;
                    if (RELU) v = fmaxf(v, 0.f);
                    if (OUT_BF16)
                        ((unsigned short*)C)[(size_t)row * N + col] = f2bf(v);
                    else
                        ((float*)C)[(size_t)row * N + col] = v;
                }
            }
        }
    }
}

// ===========================================================================
// In-place log_softmax over rows of 128 floats. One wave per row.
// ===========================================================================
__global__ __launch_bounds__(256)
void log_softmax_kernel(float* __restrict__ out, int M) {
    int gw   = (int)((blockIdx.x * blockDim.x + threadIdx.x) >> 6);
    int lane = threadIdx.x & 63;
    if (gw >= M) return;
    float* row = out + (size_t)gw * OUTC;
    float2 v = *(const float2*)(row + lane * 2);
    float m = fmaxf(v.x, v.y);
    #pragma unroll
    for (int off = 32; off; off >>= 1) m = fmaxf(m, __shfl_xor(m, off));
    float s = __expf(v.x - m) + __expf(v.y - m);
    #pragma unroll
    for (int off = 32; off; off >>= 1) s += __shfl_xor(s, off);
    float lse = m + __logf(s);
    float2 o = make_float2(v.x - lse, v.y - lse);
    *(float2*)(row + lane * 2) = o;
}

// ===========================================================================
extern "C" void kernel_launch(void* const* d_in, const int* in_sizes, int n_in,
                              void* d_out, int out_size, void* d_ws, size_t ws_size,
                              hipStream_t stream) {
    const float* x    = (const float*)d_in[0];
    const int*   ei   = (const int*)d_in[1];
    const float* eps0 = (const float*)d_in[2];
    const float* W1_0 = (const float*)d_in[3];
    const float* b1_0 = (const float*)d_in[4];
    const float* W2_0 = (const float*)d_in[5];
    const float* b2_0 = (const float*)d_in[6];
    const float* eps1 = (const float*)d_in[7];
    const float* W1_1 = (const float*)d_in[8];
    const float* b1_1 = (const float*)d_in[9];
    const float* W2_1 = (const float*)d_in[10];
    const float* b2_1 = (const float*)d_in[11];
    float* out = (float*)d_out;

    const int N = in_sizes[0] / FDIM;      // 50000
    const int E = in_sizes[1] / 2;         // 800000
    const int* src = ei;
    const int* dst = ei + E;

    size_t buf_elems = (size_t)N * FDIM;
    unsigned short* agg = (unsigned short*)d_ws;
    unsigned short* h1  = agg + buf_elems;
    unsigned short* h2  = h1 + buf_elems;
    unsigned short* wt1_0 = h2 + buf_elems;
    unsigned short* wt2_0 = wt1_0 + FDIM * FDIM;
    unsigned short* wt1_1 = wt2_0 + FDIM * FDIM;
    unsigned short* wt2_1 = wt1_1 + FDIM * FDIM;
    int* counts  = (int*)(wt2_1 + FDIM * OUTC);
    int* offsets = counts + N;
    int* cursor  = offsets + N;
    int* esrc    = cursor + N;

    int eb = (E + 255) / 256;
    int gather_blocks = (N + 3) / 4;

    // ---- CSR build (shared by both layers) ----
    hipMemsetAsync(counts, 0, (size_t)N * sizeof(int), stream);
    hipMemsetAsync(cursor, 0, (size_t)N * sizeof(int), stream);
    histogram_kernel<<<eb, 256, 0, stream>>>(dst, counts, E);
    scan_kernel<<<1, 1024, 0, stream>>>(counts, offsets, N);
    binning_kernel<<<eb, 256, 0, stream>>>(src, dst, offsets, cursor, esrc, E);

    // ---- weights -> bf16 transposed ----
    convert_wt_kernel<<<(FDIM * FDIM + 255) / 256, 256, 0, stream>>>(W1_0, wt1_0, FDIM, FDIM);
    convert_wt_kernel<<<(FDIM * FDIM + 255) / 256, 256, 0, stream>>>(W2_0, wt2_0, FDIM, FDIM);
    convert_wt_kernel<<<(FDIM * FDIM + 255) / 256, 256, 0, stream>>>(W1_1, wt1_1, FDIM, FDIM);
    convert_wt_kernel<<<(FDIM * OUTC + 255) / 256, 256, 0, stream>>>(W2_1, wt2_1, FDIM, OUTC);

    dim3 grid_h(FDIM / BN, (N + BM - 1) / BM);   // (2, 391)
    dim3 grid_o(OUTC / BN, (N + BM - 1) / BM);   // (1, 391)

    // ---- layer 0 ----
    gather_f32_kernel<<<gather_blocks, 256, 0, stream>>>(x, esrc, offsets, counts, eps0, agg, N);
    gemm_bf16_kernel<true, true><<<grid_h, 256, 0, stream>>>(agg, wt1_0, b1_0, h1, N, FDIM, FDIM);
    gemm_bf16_kernel<true, true><<<grid_h, 256, 0, stream>>>(h1, wt2_0, b2_0, h2, N, FDIM, FDIM);

    // ---- layer 1 ----
    gather_bf16_kernel<<<gather_blocks, 256, 0, stream>>>(h2, esrc, offsets, counts, eps1, agg, N);
    gemm_bf16_kernel<true, true><<<grid_h, 256, 0, stream>>>(agg, wt1_1, b1_1, h1, N, FDIM, FDIM);
    gemm_bf16_kernel<false, false><<<grid_o, 256, 0, stream>>>(h1, wt2_1, b2_1, out, N, OUTC, FDIM);

    // ---- log_softmax ----
    log_softmax_kernel<<<(N + 3) / 4, 256, 0, stream>>>(out, N);
}

// Round 4
// 543.237 us; speedup vs baseline: 10.8202x; 1.1345x over previous
//
#include <hip/hip_runtime.h>
#include <hip/hip_bf16.h>

#define FDIM 256
#define OUTC 128

typedef float floatx4 __attribute__((ext_vector_type(4)));
typedef __bf16 bf16x8 __attribute__((ext_vector_type(8)));

__device__ __forceinline__ unsigned short f2bf(float f) {
    union { float f; unsigned u; } v; v.f = f;
    unsigned r = v.u + 0x7FFF + ((v.u >> 16) & 1);   // RNE
    return (unsigned short)(r >> 16);
}
__device__ __forceinline__ float bf2f(unsigned short b) {
    union { unsigned u; float f; } v; v.u = ((unsigned)b) << 16;
    return v.f;
}
__device__ __forceinline__ unsigned pack2(float a, float b) {
    return ((unsigned)f2bf(a)) | (((unsigned)f2bf(b)) << 16);
}
__device__ __forceinline__ void acc_row(float* acc, uint4 v) {
    union { unsigned u; float f; } t;
    unsigned w0 = v.x, w1 = v.y, w2 = v.z, w3 = v.w;
    t.u = w0 << 16;        acc[0] += t.f;
    t.u = w0 & 0xffff0000; acc[1] += t.f;
    t.u = w1 << 16;        acc[2] += t.f;
    t.u = w1 & 0xffff0000; acc[3] += t.f;
    t.u = w2 << 16;        acc[4] += t.f;
    t.u = w2 & 0xffff0000; acc[5] += t.f;
    t.u = w3 << 16;        acc[6] += t.f;
    t.u = w3 & 0xffff0000; acc[7] += t.f;
}

// ===========================================================================
// CSR build: histogram -> exclusive scan -> binning
// ===========================================================================
__global__ __launch_bounds__(256)
void histogram_kernel(const int* __restrict__ dst, int* __restrict__ counts, int E) {
    int i = blockIdx.x * blockDim.x + threadIdx.x;
    if (i < E) atomicAdd(&counts[dst[i]], 1);
}

__global__ __launch_bounds__(1024)
void scan_kernel(const int* __restrict__ counts, int* __restrict__ offsets, int N) {
    __shared__ int sums[1024];
    int tid = threadIdx.x;
    int chunk = (N + 1023) >> 10;
    int begin = tid * chunk;
    int end = begin + chunk; if (end > N) end = N;
    int s = 0;
    for (int i = begin; i < end; ++i) s += counts[i];
    sums[tid] = s;
    __syncthreads();
    for (int off = 1; off < 1024; off <<= 1) {
        int t = (tid >= off) ? sums[tid - off] : 0;
        __syncthreads();
        sums[tid] += t;
        __syncthreads();
    }
    int run = sums[tid] - s;
    for (int i = begin; i < end; ++i) {
        offsets[i] = run;
        run += counts[i];
    }
}

__global__ __launch_bounds__(256)
void binning_kernel(const int* __restrict__ src, const int* __restrict__ dst,
                    const int* __restrict__ offsets, int* __restrict__ cursor,
                    int* __restrict__ esrc, int E) {
    int i = blockIdx.x * blockDim.x + threadIdx.x;
    if (i < E) {
        int d = dst[i];
        int pos = offsets[d] + atomicAdd(&cursor[d], 1);
        esrc[pos] = src[i];
    }
}

// ===========================================================================
// x fp32 -> bf16 (8 elems/thread)
// ===========================================================================
__global__ __launch_bounds__(256)
void convert_x_kernel(const float* __restrict__ x, unsigned short* __restrict__ xb,
                      long long total8) {
    long long i = (long long)blockIdx.x * blockDim.x + threadIdx.x;
    if (i >= total8) return;
    const float4* p = (const float4*)(x + i * 8);
    float4 a = p[0], b = p[1];
    uint4 o;
    o.x = pack2(a.x, a.y); o.y = pack2(a.z, a.w);
    o.z = pack2(b.x, b.y); o.w = pack2(b.z, b.w);
    *(uint4*)(xb + i * 8) = o;
}

// ===========================================================================
// All four weights -> bf16 transposed [N][K], merged into one launch.
// Segments: [0,64K) W1_0(256x256)  [64K,128K) W2_0  [128K,192K) W1_1
//           [192K,224K) W2_1(256x128)
// ===========================================================================
__global__ __launch_bounds__(256)
void convert_weights_kernel(const float* __restrict__ W1_0, const float* __restrict__ W2_0,
                            const float* __restrict__ W1_1, const float* __restrict__ W2_1,
                            unsigned short* __restrict__ wt1_0, unsigned short* __restrict__ wt2_0,
                            unsigned short* __restrict__ wt1_1, unsigned short* __restrict__ wt2_1) {
    int idx = blockIdx.x * blockDim.x + threadIdx.x;
    const int S = FDIM * FDIM;   // 65536
    const float* W; unsigned short* WT; int local, n, k, Ncols;
    if (idx < S)            { W = W1_0; WT = wt1_0; local = idx;         Ncols = FDIM; }
    else if (idx < 2 * S)   { W = W2_0; WT = wt2_0; local = idx - S;     Ncols = FDIM; }
    else if (idx < 3 * S)   { W = W1_1; WT = wt1_1; local = idx - 2 * S; Ncols = FDIM; }
    else if (idx < 3 * S + FDIM * OUTC)
                            { W = W2_1; WT = wt2_1; local = idx - 3 * S; Ncols = OUTC; }
    else return;
    n = local >> 8;            // / K (K==256)
    k = local & 255;
    WT[local] = f2bf(W[(size_t)k * Ncols + n]);
}

// ===========================================================================
// Gather-aggregate: out[n] = (1+eps)*self[n] + sum_{s in nbr(n)} xb[s]   (bf16 out)
// One wave per node. Row = 256 bf16 = 512B = 32 lanes x 16B, so each wave
// processes TWO edges per iteration (half-wave each), unrolled x2.
// SELF_F32: self term read from fp32 xf; else from xb.
// ===========================================================================
template<bool SELF_F32>
__global__ __launch_bounds__(256)
void gather2_kernel(const unsigned short* __restrict__ xb,
                    const float* __restrict__ xf,
                    const int* __restrict__ esrc,
                    const int* __restrict__ offsets, const int* __restrict__ counts,
                    const float* __restrict__ epsp, unsigned short* __restrict__ out,
                    int N) {
    int node = (int)((blockIdx.x * blockDim.x + threadIdx.x) >> 6);
    int lane = threadIdx.x & 63;
    if (node >= N) return;
    int half = lane >> 5;      // which edge of the pair
    int hl   = lane & 31;      // 16B chunk within row
    int beg = offsets[node];
    int cnt = counts[node];

    float acc[8] = {0.f, 0.f, 0.f, 0.f, 0.f, 0.f, 0.f, 0.f};

    int e = 0;
    for (; e + 4 <= cnt; e += 4) {
        int s0 = esrc[beg + e + half];
        int s1 = esrc[beg + e + 2 + half];
        uint4 v0 = *(const uint4*)(xb + (size_t)s0 * FDIM + hl * 8);
        uint4 v1 = *(const uint4*)(xb + (size_t)s1 * FDIM + hl * 8);
        acc_row(acc, v0);
        acc_row(acc, v1);
    }
    if (e + 2 <= cnt) {
        int s0 = esrc[beg + e + half];
        uint4 v0 = *(const uint4*)(xb + (size_t)s0 * FDIM + hl * 8);
        acc_row(acc, v0);
        e += 2;
    }
    if (e < cnt && half == 0) {
        int s0 = esrc[beg + e];
        uint4 v0 = *(const uint4*)(xb + (size_t)s0 * FDIM + hl * 8);
        acc_row(acc, v0);
    }

    // combine the two half-wave partial sums
    #pragma unroll
    for (int i = 0; i < 8; ++i) acc[i] += __shfl_xor(acc[i], 32);

    if (half == 0) {
        float scale = 1.0f + *epsp;
        if (SELF_F32) {
            const float4* p = (const float4*)(xf + (size_t)node * FDIM + hl * 8);
            float4 a = p[0], b = p[1];
            acc[0] += scale * a.x; acc[1] += scale * a.y;
            acc[2] += scale * a.z; acc[3] += scale * a.w;
            acc[4] += scale * b.x; acc[5] += scale * b.y;
            acc[6] += scale * b.z; acc[7] += scale * b.w;
        } else {
            uint4 v = *(const uint4*)(xb + (size_t)node * FDIM + hl * 8);
            float sv[8];
            union { unsigned u; float f; } t;
            t.u = v.x << 16;        sv[0] = t.f;
            t.u = v.x & 0xffff0000; sv[1] = t.f;
            t.u = v.y << 16;        sv[2] = t.f;
            t.u = v.y & 0xffff0000; sv[3] = t.f;
            t.u = v.z << 16;        sv[4] = t.f;
            t.u = v.z & 0xffff0000; sv[5] = t.f;
            t.u = v.w << 16;        sv[6] = t.f;
            t.u = v.w & 0xffff0000; sv[7] = t.f;
            #pragma unroll
            for (int i = 0; i < 8; ++i) acc[i] += scale * sv[i];
        }
        uint4 o;
        o.x = pack2(acc[0], acc[1]);
        o.y = pack2(acc[2], acc[3]);
        o.z = pack2(acc[4], acc[5]);
        o.w = pack2(acc[6], acc[7]);
        *(uint4*)(out + (size_t)node * FDIM + hl * 8) = o;
    }
}

// ===========================================================================
// bf16 MFMA GEMM: C[M,N] = A[M,K] @ WT[N,K]^T + bias, optional ReLU.
// BM=128, BN=128, BK=64; 256 threads = 4 waves (2x2), each wave 64x64 via
// 4x4 grid of mfma_f32_16x16x32_bf16. LDS stride padded to 72 (2-way = free).
// ===========================================================================
#define BM 128
#define BN 128
#define BK 64
#define LDK 72

template<bool RELU, bool OUT_BF16>
__global__ __launch_bounds__(256)
void gemm_bf16_kernel(const unsigned short* __restrict__ A,   // [M,K] bf16
                      const unsigned short* __restrict__ WT,  // [N,K] bf16
                      const float* __restrict__ bias,         // [N]
                      void* __restrict__ C,                   // [M,N]
                      int M, int N, int K) {
    __shared__ unsigned short As[BM * LDK];
    __shared__ unsigned short Bs[BN * LDK];

    int tid  = threadIdx.x;
    int wave = tid >> 6;
    int lane = tid & 63;
    int wr   = wave >> 1;
    int wc   = wave & 1;
    int l15  = lane & 15;
    int quad = lane >> 4;

    int row0 = blockIdx.y * BM;
    int col0 = blockIdx.x * BN;

    floatx4 zero = {0.f, 0.f, 0.f, 0.f};
    floatx4 acc[4][4];
    #pragma unroll
    for (int i = 0; i < 4; ++i)
        #pragma unroll
        for (int j = 0; j < 4; ++j) acc[i][j] = zero;

    int srow = tid >> 3;
    int sck  = tid & 7;

    for (int kb = 0; kb < K; kb += BK) {
        #pragma unroll
        for (int i = 0; i < 4; ++i) {
            int r = srow + i * 32;
            int gr = row0 + r;
            uint4 v = make_uint4(0u, 0u, 0u, 0u);
            if (gr < M) v = *(const uint4*)(A + (size_t)gr * K + kb + sck * 8);
            *(uint4*)(As + r * LDK + sck * 8) = v;
        }
        #pragma unroll
        for (int i = 0; i < 4; ++i) {
            int r = srow + i * 32;
            uint4 v = *(const uint4*)(WT + (size_t)(col0 + r) * K + kb + sck * 8);
            *(uint4*)(Bs + r * LDK + sck * 8) = v;
        }
        __syncthreads();

        #pragma unroll
        for (int ks = 0; ks < 2; ++ks) {
            bf16x8 af[4], bfr[4];
            #pragma unroll
            for (int i = 0; i < 4; ++i)
                af[i] = *(const bf16x8*)(As + (wr * 64 + i * 16 + l15) * LDK + ks * 32 + quad * 8);
            #pragma unroll
            for (int j = 0; j < 4; ++j)
                bfr[j] = *(const bf16x8*)(Bs + (wc * 64 + j * 16 + l15) * LDK + ks * 32 + quad * 8);
            #pragma unroll
            for (int i = 0; i < 4; ++i)
                #pragma unroll
                for (int j = 0; j < 4; ++j)
                    acc[i][j] = __builtin_amdgcn_mfma_f32_16x16x32_bf16(
                        af[i], bfr[j], acc[i][j], 0, 0, 0);
        }
        __syncthreads();
    }

    #pragma unroll
    for (int j = 0; j < 4; ++j) {
        int col = col0 + wc * 64 + j * 16 + l15;
        float bv = bias[col];
        #pragma unroll
        for (int i = 0; i < 4; ++i) {
            int rbase = row0 + wr * 64 + i * 16 + quad * 4;
            #pragma unroll
            for (int r = 0; r < 4; ++r) {
                int row = rbase + r;
                if (row < M) {
                    float v = acc[i][j][r] + bv;
                    if (RELU) v = fmaxf(v, 0.f);
                    if (OUT_BF16)
                        ((unsigned short*)C)[(size_t)row * N + col] = f2bf(v);
                    else
                        ((float*)C)[(size_t)row * N + col] = v;
                }
            }
        }
    }
}

// ===========================================================================
// In-place log_softmax over rows of 128 floats. One wave per row.
// ===========================================================================
__global__ __launch_bounds__(256)
void log_softmax_kernel(float* __restrict__ out, int M) {
    int gw   = (int)((blockIdx.x * blockDim.x + threadIdx.x) >> 6);
    int lane = threadIdx.x & 63;
    if (gw >= M) return;
    float* row = out + (size_t)gw * OUTC;
    float2 v = *(const float2*)(row + lane * 2);
    float m = fmaxf(v.x, v.y);
    #pragma unroll
    for (int off = 32; off; off >>= 1) m = fmaxf(m, __shfl_xor(m, off));
    float s = __expf(v.x - m) + __expf(v.y - m);
    #pragma unroll
    for (int off = 32; off; off >>= 1) s += __shfl_xor(s, off);
    float lse = m + __logf(s);
    float2 o = make_float2(v.x - lse, v.y - lse);
    *(float2*)(row + lane * 2) = o;
}

// ===========================================================================
extern "C" void kernel_launch(void* const* d_in, const int* in_sizes, int n_in,
                              void* d_out, int out_size, void* d_ws, size_t ws_size,
                              hipStream_t stream) {
    const float* x    = (const float*)d_in[0];
    const int*   ei   = (const int*)d_in[1];
    const float* eps0 = (const float*)d_in[2];
    const float* W1_0 = (const float*)d_in[3];
    const float* b1_0 = (const float*)d_in[4];
    const float* W2_0 = (const float*)d_in[5];
    const float* b2_0 = (const float*)d_in[6];
    const float* eps1 = (const float*)d_in[7];
    const float* W1_1 = (const float*)d_in[8];
    const float* b1_1 = (const float*)d_in[9];
    const float* W2_1 = (const float*)d_in[10];
    const float* b2_1 = (const float*)d_in[11];
    float* out = (float*)d_out;

    const int N = in_sizes[0] / FDIM;      // 50000
    const int E = in_sizes[1] / 2;         // 800000
    const int* src = ei;
    const int* dst = ei + E;

    size_t buf_elems = (size_t)N * FDIM;
    unsigned short* agg = (unsigned short*)d_ws;
    unsigned short* h1  = agg + buf_elems;
    unsigned short* h2  = h1 + buf_elems;
    unsigned short* xb  = h2 + buf_elems;
    unsigned short* wt1_0 = xb + buf_elems;
    unsigned short* wt2_0 = wt1_0 + FDIM * FDIM;
    unsigned short* wt1_1 = wt2_0 + FDIM * FDIM;
    unsigned short* wt2_1 = wt1_1 + FDIM * FDIM;
    int* counts  = (int*)(wt2_1 + FDIM * OUTC);
    int* offsets = counts + N;
    int* cursor  = offsets + N;
    int* esrc    = cursor + N;

    int eb = (E + 255) / 256;
    int gather_blocks = (N + 3) / 4;

    // ---- CSR build (shared by both layers) ----
    hipMemsetAsync(counts, 0, (size_t)N * sizeof(int), stream);
    hipMemsetAsync(cursor, 0, (size_t)N * sizeof(int), stream);
    histogram_kernel<<<eb, 256, 0, stream>>>(dst, counts, E);
    scan_kernel<<<1, 1024, 0, stream>>>(counts, offsets, N);
    binning_kernel<<<eb, 256, 0, stream>>>(src, dst, offsets, cursor, esrc, E);

    // ---- converts ----
    long long total8 = (long long)buf_elems / 8;
    convert_x_kernel<<<(int)((total8 + 255) / 256), 256, 0, stream>>>(x, xb, total8);
    int wtot = 3 * FDIM * FDIM + FDIM * OUTC;
    convert_weights_kernel<<<(wtot + 255) / 256, 256, 0, stream>>>(
        W1_0, W2_0, W1_1, W2_1, wt1_0, wt2_0, wt1_1, wt2_1);

    dim3 grid_h(FDIM / BN, (N + BM - 1) / BM);
    dim3 grid_o(OUTC / BN, (N + BM - 1) / BM);

    // ---- layer 0 ----
    gather2_kernel<true><<<gather_blocks, 256, 0, stream>>>(
        xb, x, esrc, offsets, counts, eps0, agg, N);
    gemm_bf16_kernel<true, true><<<grid_h, 256, 0, stream>>>(agg, wt1_0, b1_0, h1, N, FDIM, FDIM);
    gemm_bf16_kernel<true, true><<<grid_h, 256, 0, stream>>>(h1, wt2_0, b2_0, h2, N, FDIM, FDIM);

    // ---- layer 1 ----
    gather2_kernel<false><<<gather_blocks, 256, 0, stream>>>(
        h2, nullptr, esrc, offsets, counts, eps1, agg, N);
    gemm_bf16_kernel<true, true><<<grid_h, 256, 0, stream>>>(agg, wt1_1, b1_1, h1, N, FDIM, FDIM);
    gemm_bf16_kernel<false, false><<<grid_o, 256, 0, stream>>>(h1, wt2_1, b2_1, out, N, OUTC, FDIM);

    // ---- log_softmax ----
    log_softmax_kernel<<<(N + 3) / 4, 256, 0, stream>>>(out, N);
}

// Round 6
// 460.560 us; speedup vs baseline: 12.7626x; 1.1795x over previous
//
#include <hip/hip_runtime.h>
#include <hip/hip_bf16.h>

#define FDIM 256
#define OUTC 128

typedef float floatx4 __attribute__((ext_vector_type(4)));
typedef __bf16 bf16x8 __attribute__((ext_vector_type(8)));

__device__ __forceinline__ unsigned short f2bf(float f) {
    union { float f; unsigned u; } v; v.f = f;
    unsigned r = v.u + 0x7FFF + ((v.u >> 16) & 1);   // RNE
    return (unsigned short)(r >> 16);
}
__device__ __forceinline__ float bf2f(unsigned short b) {
    union { unsigned u; float f; } v; v.u = ((unsigned)b) << 16;
    return v.f;
}
__device__ __forceinline__ unsigned pack2(float a, float b) {
    return ((unsigned)f2bf(a)) | (((unsigned)f2bf(b)) << 16);
}
__device__ __forceinline__ void acc_row(float* acc, uint4 v) {
    union { unsigned u; float f; } t;
    unsigned w0 = v.x, w1 = v.y, w2 = v.z, w3 = v.w;
    t.u = w0 << 16;        acc[0] += t.f;
    t.u = w0 & 0xffff0000; acc[1] += t.f;
    t.u = w1 << 16;        acc[2] += t.f;
    t.u = w1 & 0xffff0000; acc[3] += t.f;
    t.u = w2 << 16;        acc[4] += t.f;
    t.u = w2 & 0xffff0000; acc[5] += t.f;
    t.u = w3 << 16;        acc[6] += t.f;
    t.u = w3 & 0xffff0000; acc[7] += t.f;
}

// ===========================================================================
// CSR build: histogram -> 3-kernel multi-block scan -> binning
// ===========================================================================
__global__ __launch_bounds__(256)
void histogram_kernel(const int* __restrict__ dst, int* __restrict__ counts, int E) {
    int i = blockIdx.x * blockDim.x + threadIdx.x;
    if (i < E) atomicAdd(&counts[dst[i]], 1);
}

// one block per 256 counts -> block sum
__global__ __launch_bounds__(256)
void block_sums_kernel(const int* __restrict__ counts, int* __restrict__ partials, int N) {
    int i = blockIdx.x * 256 + threadIdx.x;
    int v = (i < N) ? counts[i] : 0;
    #pragma unroll
    for (int off = 32; off; off >>= 1) v += __shfl_down(v, off);
    __shared__ int ws[4];
    if ((threadIdx.x & 63) == 0) ws[threadIdx.x >> 6] = v;
    __syncthreads();
    if (threadIdx.x == 0) partials[blockIdx.x] = ws[0] + ws[1] + ws[2] + ws[3];
}

// single block: exclusive scan of up to 1024 partials
__global__ __launch_bounds__(1024)
void scan_partials_kernel(int* __restrict__ partials, int nchunks) {
    __shared__ int s[1024];
    int tid = threadIdx.x;
    int v = (tid < nchunks) ? partials[tid] : 0;
    s[tid] = v;
    __syncthreads();
    for (int off = 1; off < 1024; off <<= 1) {
        int t = (tid >= off) ? s[tid - off] : 0;
        __syncthreads();
        s[tid] += t;
        __syncthreads();
    }
    if (tid < nchunks) partials[tid] = s[tid] - v;   // exclusive
}

// per-chunk exclusive scan + base; writes offsets and cursor (cursor=offsets)
__global__ __launch_bounds__(256)
void chunk_scan_kernel(const int* __restrict__ counts, const int* __restrict__ partials,
                       int* __restrict__ offsets, int* __restrict__ cursor, int N) {
    int tid = threadIdx.x;
    int i = blockIdx.x * 256 + tid;
    int v = (i < N) ? counts[i] : 0;
    int lane = tid & 63;
    int incl = v;
    #pragma unroll
    for (int off = 1; off < 64; off <<= 1) {
        int t = __shfl_up(incl, off);
        if (lane >= off) incl += t;
    }
    __shared__ int wsum[4];
    if (lane == 63) wsum[tid >> 6] = incl;
    __syncthreads();
    int w = tid >> 6;
    int add = partials[blockIdx.x];
    for (int k = 0; k < w; ++k) add += wsum[k];
    int excl = add + incl - v;
    if (i < N) { offsets[i] = excl; cursor[i] = excl; }
}

__global__ __launch_bounds__(256)
void binning_kernel(const int* __restrict__ src, const int* __restrict__ dst,
                    int* __restrict__ cursor, int* __restrict__ esrc, int E) {
    int i = blockIdx.x * blockDim.x + threadIdx.x;
    if (i < E) {
        int d = dst[i];
        int pos = atomicAdd(&cursor[d], 1);
        esrc[pos] = src[i];
    }
}

// ===========================================================================
// x fp32 -> bf16 (8 elems/thread)
// ===========================================================================
__global__ __launch_bounds__(256)
void convert_x_kernel(const float* __restrict__ x, unsigned short* __restrict__ xb,
                      long long total8) {
    long long i = (long long)blockIdx.x * blockDim.x + threadIdx.x;
    if (i >= total8) return;
    const float4* p = (const float4*)(x + i * 8);
    float4 a = p[0], b = p[1];
    uint4 o;
    o.x = pack2(a.x, a.y); o.y = pack2(a.z, a.w);
    o.z = pack2(b.x, b.y); o.w = pack2(b.z, b.w);
    *(uint4*)(xb + i * 8) = o;
}

// ===========================================================================
// All four weights -> bf16 transposed [N][K], one launch.
// ===========================================================================
__global__ __launch_bounds__(256)
void convert_weights_kernel(const float* __restrict__ W1_0, const float* __restrict__ W2_0,
                            const float* __restrict__ W1_1, const float* __restrict__ W2_1,
                            unsigned short* __restrict__ wt1_0, unsigned short* __restrict__ wt2_0,
                            unsigned short* __restrict__ wt1_1, unsigned short* __restrict__ wt2_1) {
    int idx = blockIdx.x * blockDim.x + threadIdx.x;
    const int S = FDIM * FDIM;
    const float* W; unsigned short* WT; int local, n, k, Ncols;
    if (idx < S)            { W = W1_0; WT = wt1_0; local = idx;         Ncols = FDIM; }
    else if (idx < 2 * S)   { W = W2_0; WT = wt2_0; local = idx - S;     Ncols = FDIM; }
    else if (idx < 3 * S)   { W = W1_1; WT = wt1_1; local = idx - 2 * S; Ncols = FDIM; }
    else if (idx < 3 * S + FDIM * OUTC)
                            { W = W2_1; WT = wt2_1; local = idx - 3 * S; Ncols = OUTC; }
    else return;
    n = local >> 8;
    k = local & 255;
    WT[local] = f2bf(W[(size_t)k * Ncols + n]);
}

// ===========================================================================
// Gather-aggregate: out[n] = (1+eps)*self[n] + sum xb[src]. One wave per node;
// half-wave per edge (32 lanes x 16B = 512B row), 8 edges per main iter.
// ===========================================================================
template<bool SELF_F32>
__global__ __launch_bounds__(256)
void gather2_kernel(const unsigned short* __restrict__ xb,
                    const float* __restrict__ xf,
                    const int* __restrict__ esrc,
                    const int* __restrict__ offsets, const int* __restrict__ counts,
                    const float* __restrict__ epsp, unsigned short* __restrict__ out,
                    int N) {
    int node = (int)((blockIdx.x * blockDim.x + threadIdx.x) >> 6);
    int lane = threadIdx.x & 63;
    if (node >= N) return;
    int half = lane >> 5;
    int hl   = lane & 31;
    int beg = offsets[node];
    int cnt = counts[node];

    float acc[8] = {0.f, 0.f, 0.f, 0.f, 0.f, 0.f, 0.f, 0.f};

    int e = 0;
    for (; e + 8 <= cnt; e += 8) {
        int s0 = esrc[beg + e + half];
        int s1 = esrc[beg + e + 2 + half];
        int s2 = esrc[beg + e + 4 + half];
        int s3 = esrc[beg + e + 6 + half];
        uint4 v0 = *(const uint4*)(xb + (size_t)s0 * FDIM + hl * 8);
        uint4 v1 = *(const uint4*)(xb + (size_t)s1 * FDIM + hl * 8);
        uint4 v2 = *(const uint4*)(xb + (size_t)s2 * FDIM + hl * 8);
        uint4 v3 = *(const uint4*)(xb + (size_t)s3 * FDIM + hl * 8);
        acc_row(acc, v0);
        acc_row(acc, v1);
        acc_row(acc, v2);
        acc_row(acc, v3);
    }
    for (; e + 2 <= cnt; e += 2) {
        int s0 = esrc[beg + e + half];
        uint4 v0 = *(const uint4*)(xb + (size_t)s0 * FDIM + hl * 8);
        acc_row(acc, v0);
    }
    if (e < cnt && half == 0) {
        int s0 = esrc[beg + e];
        uint4 v0 = *(const uint4*)(xb + (size_t)s0 * FDIM + hl * 8);
        acc_row(acc, v0);
    }

    #pragma unroll
    for (int i = 0; i < 8; ++i) acc[i] += __shfl_xor(acc[i], 32);

    if (half == 0) {
        float scale = 1.0f + *epsp;
        if (SELF_F32) {
            const float4* p = (const float4*)(xf + (size_t)node * FDIM + hl * 8);
            float4 a = p[0], b = p[1];
            acc[0] += scale * a.x; acc[1] += scale * a.y;
            acc[2] += scale * a.z; acc[3] += scale * a.w;
            acc[4] += scale * b.x; acc[5] += scale * b.y;
            acc[6] += scale * b.z; acc[7] += scale * b.w;
        } else {
            uint4 v = *(const uint4*)(xb + (size_t)node * FDIM + hl * 8);
            float sv[8];
            union { unsigned u; float f; } t;
            t.u = v.x << 16;        sv[0] = t.f;
            t.u = v.x & 0xffff0000; sv[1] = t.f;
            t.u = v.y << 16;        sv[2] = t.f;
            t.u = v.y & 0xffff0000; sv[3] = t.f;
            t.u = v.z << 16;        sv[4] = t.f;
            t.u = v.z & 0xffff0000; sv[5] = t.f;
            t.u = v.w << 16;        sv[6] = t.f;
            t.u = v.w & 0xffff0000; sv[7] = t.f;
            #pragma unroll
            for (int i = 0; i < 8; ++i) acc[i] += scale * sv[i];
        }
        uint4 o;
        o.x = pack2(acc[0], acc[1]);
        o.y = pack2(acc[2], acc[3]);
        o.z = pack2(acc[4], acc[5]);
        o.w = pack2(acc[6], acc[7]);
        *(uint4*)(out + (size_t)node * FDIM + hl * 8) = o;
    }
}

// ===========================================================================
// bf16 MFMA GEMM: C[M,N] = A[M,K] @ WT[N,K]^T + bias, ReLU, bf16 out.
// BM=128, BN=128, BK=64; 4 waves 2x2, each 64x64 via 4x4 mfma_16x16x32_bf16.
// ===========================================================================
#define BM 128
#define BN 128
#define BK 64
#define LDK 72

__global__ __launch_bounds__(256)
void gemm_bf16_kernel(const unsigned short* __restrict__ A,
                      const unsigned short* __restrict__ WT,
                      const float* __restrict__ bias,
                      unsigned short* __restrict__ C,
                      int M, int N, int K) {
    __shared__ unsigned short As[BM * LDK];
    __shared__ unsigned short Bs[BN * LDK];

    int tid  = threadIdx.x;
    int wave = tid >> 6;
    int lane = tid & 63;
    int wr   = wave >> 1;
    int wc   = wave & 1;
    int l15  = lane & 15;
    int quad = lane >> 4;

    int row0 = blockIdx.y * BM;
    int col0 = blockIdx.x * BN;

    floatx4 zero = {0.f, 0.f, 0.f, 0.f};
    floatx4 acc[4][4];
    #pragma unroll
    for (int i = 0; i < 4; ++i)
        #pragma unroll
        for (int j = 0; j < 4; ++j) acc[i][j] = zero;

    int srow = tid >> 3;
    int sck  = tid & 7;

    for (int kb = 0; kb < K; kb += BK) {
        #pragma unroll
        for (int i = 0; i < 4; ++i) {
            int r = srow + i * 32;
            int gr = row0 + r;
            uint4 v = make_uint4(0u, 0u, 0u, 0u);
            if (gr < M) v = *(const uint4*)(A + (size_t)gr * K + kb + sck * 8);
            *(uint4*)(As + r * LDK + sck * 8) = v;
        }
        #pragma unroll
        for (int i = 0; i < 4; ++i) {
            int r = srow + i * 32;
            uint4 v = *(const uint4*)(WT + (size_t)(col0 + r) * K + kb + sck * 8);
            *(uint4*)(Bs + r * LDK + sck * 8) = v;
        }
        __syncthreads();

        #pragma unroll
        for (int ks = 0; ks < 2; ++ks) {
            bf16x8 af[4], bfr[4];
            #pragma unroll
            for (int i = 0; i < 4; ++i)
                af[i] = *(const bf16x8*)(As + (wr * 64 + i * 16 + l15) * LDK + ks * 32 + quad * 8);
            #pragma unroll
            for (int j = 0; j < 4; ++j)
                bfr[j] = *(const bf16x8*)(Bs + (wc * 64 + j * 16 + l15) * LDK + ks * 32 + quad * 8);
            #pragma unroll
            for (int i = 0; i < 4; ++i)
                #pragma unroll
                for (int j = 0; j < 4; ++j)
                    acc[i][j] = __builtin_amdgcn_mfma_f32_16x16x32_bf16(
                        af[i], bfr[j], acc[i][j], 0, 0, 0);
        }
        __syncthreads();
    }

    #pragma unroll
    for (int j = 0; j < 4; ++j) {
        int col = col0 + wc * 64 + j * 16 + l15;
        float bv = bias[col];
        #pragma unroll
        for (int i = 0; i < 4; ++i) {
            int rbase = row0 + wr * 64 + i * 16 + quad * 4;
            #pragma unroll
            for (int r = 0; r < 4; ++r) {
                int row = rbase + r;
                if (row < M) {
                    float v = fmaxf(acc[i][j][r] + bv, 0.f);
                    C[(size_t)row * N + col] = f2bf(v);
                }
            }
        }
    }
}

// ===========================================================================
// Final GEMM (N=128, one block covers full rows) + fused log_softmax.
// Output fp32.
// ===========================================================================
__global__ __launch_bounds__(256)
void gemm_softmax_kernel(const unsigned short* __restrict__ A,
                         const unsigned short* __restrict__ WT,
                         const float* __restrict__ bias,
                         float* __restrict__ Out,
                         int Mrows, int K) {
    __shared__ unsigned short As[BM * LDK];
    __shared__ unsigned short Bs[OUTC * LDK];
    __shared__ float smax[BM * 2];
    __shared__ float ssum[BM * 2];

    int tid  = threadIdx.x;
    int wave = tid >> 6;
    int lane = tid & 63;
    int wr   = wave >> 1;
    int wc   = wave & 1;
    int l15  = lane & 15;
    int quad = lane >> 4;

    int row0 = blockIdx.y * BM;

    floatx4 zero = {0.f, 0.f, 0.f, 0.f};
    floatx4 acc[4][4];
    #pragma unroll
    for (int i = 0; i < 4; ++i)
        #pragma unroll
        for (int j = 0; j < 4; ++j) acc[i][j] = zero;

    int srow = tid >> 3;
    int sck  = tid & 7;

    for (int kb = 0; kb < K; kb += BK) {
        #pragma unroll
        for (int i = 0; i < 4; ++i) {
            int r = srow + i * 32;
            int gr = row0 + r;
            uint4 v = make_uint4(0u, 0u, 0u, 0u);
            if (gr < Mrows) v = *(const uint4*)(A + (size_t)gr * K + kb + sck * 8);
            *(uint4*)(As + r * LDK + sck * 8) = v;
        }
        // B: 128 rows = 4 iterations of 32 rows (same as unfused kernel)
        #pragma unroll
        for (int i = 0; i < 4; ++i) {
            int r = srow + i * 32;
            uint4 v = *(const uint4*)(WT + (size_t)r * K + kb + sck * 8);
            *(uint4*)(Bs + r * LDK + sck * 8) = v;
        }
        __syncthreads();

        #pragma unroll
        for (int ks = 0; ks < 2; ++ks) {
            bf16x8 af[4], bfr[4];
            #pragma unroll
            for (int i = 0; i < 4; ++i)
                af[i] = *(const bf16x8*)(As + (wr * 64 + i * 16 + l15) * LDK + ks * 32 + quad * 8);
            #pragma unroll
            for (int j = 0; j < 4; ++j)
                bfr[j] = *(const bf16x8*)(Bs + (wc * 64 + j * 16 + l15) * LDK + ks * 32 + quad * 8);
            #pragma unroll
            for (int i = 0; i < 4; ++i)
                #pragma unroll
                for (int j = 0; j < 4; ++j)
                    acc[i][j] = __builtin_amdgcn_mfma_f32_16x16x32_bf16(
                        af[i], bfr[j], acc[i][j], 0, 0, 0);
        }
        __syncthreads();
    }

    // add bias in place
    #pragma unroll
    for (int j = 0; j < 4; ++j) {
        float bv = bias[wc * 64 + j * 16 + l15];
        #pragma unroll
        for (int i = 0; i < 4; ++i)
            #pragma unroll
            for (int r = 0; r < 4; ++r) acc[i][j][r] += bv;
    }

    // phase 1: per-row max (butterfly over the 16 lanes sharing a quad)
    #pragma unroll
    for (int i = 0; i < 4; ++i) {
        #pragma unroll
        for (int r = 0; r < 4; ++r) {
            float m = fmaxf(fmaxf(acc[i][0][r], acc[i][1][r]),
                            fmaxf(acc[i][2][r], acc[i][3][r]));
            #pragma unroll
            for (int off = 1; off < 16; off <<= 1) m = fmaxf(m, __shfl_xor(m, off));
            int row = wr * 64 + i * 16 + quad * 4 + r;
            if (l15 == 0) smax[row * 2 + wc] = m;
        }
    }
    __syncthreads();

    // phase 2: per-row sum of exp
    float Mloc[4][4];
    #pragma unroll
    for (int i = 0; i < 4; ++i) {
        #pragma unroll
        for (int r = 0; r < 4; ++r) {
            int row = wr * 64 + i * 16 + quad * 4 + r;
            float Mr = fmaxf(smax[row * 2], smax[row * 2 + 1]);
            Mloc[i][r] = Mr;
            float s = __expf(acc[i][0][r] - Mr) + __expf(acc[i][1][r] - Mr)
                    + __expf(acc[i][2][r] - Mr) + __expf(acc[i][3][r] - Mr);
            #pragma unroll
            for (int off = 1; off < 16; off <<= 1) s += __shfl_xor(s, off);
            if (l15 == 0) ssum[row * 2 + wc] = s;
        }
    }
    __syncthreads();

    // phase 3: write v - lse
    #pragma unroll
    for (int i = 0; i < 4; ++i) {
        #pragma unroll
        for (int r = 0; r < 4; ++r) {
            int row = wr * 64 + i * 16 + quad * 4 + r;
            int grow = row0 + row;
            if (grow < Mrows) {
                float lse = Mloc[i][r] + __logf(ssum[row * 2] + ssum[row * 2 + 1]);
                #pragma unroll
                for (int j = 0; j < 4; ++j) {
                    int col = wc * 64 + j * 16 + l15;
                    Out[(size_t)grow * OUTC + col] = acc[i][j][r] - lse;
                }
            }
        }
    }
}

// ===========================================================================
extern "C" void kernel_launch(void* const* d_in, const int* in_sizes, int n_in,
                              void* d_out, int out_size, void* d_ws, size_t ws_size,
                              hipStream_t stream) {
    const float* x    = (const float*)d_in[0];
    const int*   ei   = (const int*)d_in[1];
    const float* eps0 = (const float*)d_in[2];
    const float* W1_0 = (const float*)d_in[3];
    const float* b1_0 = (const float*)d_in[4];
    const float* W2_0 = (const float*)d_in[5];
    const float* b2_0 = (const float*)d_in[6];
    const float* eps1 = (const float*)d_in[7];
    const float* W1_1 = (const float*)d_in[8];
    const float* b1_1 = (const float*)d_in[9];
    const float* W2_1 = (const float*)d_in[10];
    const float* b2_1 = (const float*)d_in[11];
    float* out = (float*)d_out;

    const int N = in_sizes[0] / FDIM;      // 50000
    const int E = in_sizes[1] / 2;         // 800000
    const int* src = ei;
    const int* dst = ei + E;

    size_t buf_elems = (size_t)N * FDIM;
    unsigned short* agg = (unsigned short*)d_ws;
    unsigned short* h1  = agg + buf_elems;
    unsigned short* h2  = h1 + buf_elems;
    unsigned short* xb  = h2 + buf_elems;
    unsigned short* wt1_0 = xb + buf_elems;
    unsigned short* wt2_0 = wt1_0 + FDIM * FDIM;
    unsigned short* wt1_1 = wt2_0 + FDIM * FDIM;
    unsigned short* wt2_1 = wt1_1 + FDIM * FDIM;
    int* counts  = (int*)(wt2_1 + FDIM * OUTC);
    int* offsets = counts + N;
    int* cursor  = offsets + N;
    int* esrc    = cursor + N;
    int* partials = esrc + E;

    int eb = (E + 255) / 256;
    int gather_blocks = (N + 3) / 4;
    int nchunks = (N + 255) / 256;

    // ---- CSR build ----
    hipMemsetAsync(counts, 0, (size_t)N * sizeof(int), stream);
    histogram_kernel<<<eb, 256, 0, stream>>>(dst, counts, E);
    block_sums_kernel<<<nchunks, 256, 0, stream>>>(counts, partials, N);
    scan_partials_kernel<<<1, 1024, 0, stream>>>(partials, nchunks);
    chunk_scan_kernel<<<nchunks, 256, 0, stream>>>(counts, partials, offsets, cursor, N);
    binning_kernel<<<eb, 256, 0, stream>>>(src, dst, cursor, esrc, E);

    // ---- converts ----
    long long total8 = (long long)buf_elems / 8;
    convert_x_kernel<<<(int)((total8 + 255) / 256), 256, 0, stream>>>(x, xb, total8);
    int wtot = 3 * FDIM * FDIM + FDIM * OUTC;
    convert_weights_kernel<<<(wtot + 255) / 256, 256, 0, stream>>>(
        W1_0, W2_0, W1_1, W2_1, wt1_0, wt2_0, wt1_1, wt2_1);

    dim3 grid_h(FDIM / BN, (N + BM - 1) / BM);
    dim3 grid_o(1, (N + BM - 1) / BM);

    // ---- layer 0 ----
    gather2_kernel<true><<<gather_blocks, 256, 0, stream>>>(
        xb, x, esrc, offsets, counts, eps0, agg, N);
    gemm_bf16_kernel<<<grid_h, 256, 0, stream>>>(agg, wt1_0, b1_0, h1, N, FDIM, FDIM);
    gemm_bf16_kernel<<<grid_h, 256, 0, stream>>>(h1, wt2_0, b2_0, h2, N, FDIM, FDIM);

    // ---- layer 1 ----
    gather2_kernel<false><<<gather_blocks, 256, 0, stream>>>(
        h2, nullptr, esrc, offsets, counts, eps1, agg, N);
    gemm_bf16_kernel<<<grid_h, 256, 0, stream>>>(agg, wt1_1, b1_1, h1, N, FDIM, FDIM);
    gemm_softmax_kernel<<<grid_o, 256, 0, stream>>>(h1, wt2_1, b2_1, out, N, FDIM);
}

// Round 7
// 428.447 us; speedup vs baseline: 13.7191x; 1.0750x over previous
//
#include <hip/hip_runtime.h>
#include <hip/hip_bf16.h>

#define FDIM 256
#define OUTC 128

typedef float floatx4 __attribute__((ext_vector_type(4)));
typedef __bf16 bf16x8 __attribute__((ext_vector_type(8)));

__device__ __forceinline__ unsigned short f2bf(float f) {
    union { float f; unsigned u; } v; v.f = f;
    unsigned r = v.u + 0x7FFF + ((v.u >> 16) & 1);   // RNE
    return (unsigned short)(r >> 16);
}
__device__ __forceinline__ unsigned pack2(float a, float b) {
    return ((unsigned)f2bf(a)) | (((unsigned)f2bf(b)) << 16);
}
__device__ __forceinline__ void acc_row(float* acc, uint4 v) {
    union { unsigned u; float f; } t;
    unsigned w0 = v.x, w1 = v.y, w2 = v.z, w3 = v.w;
    t.u = w0 << 16;        acc[0] += t.f;
    t.u = w0 & 0xffff0000; acc[1] += t.f;
    t.u = w1 << 16;        acc[2] += t.f;
    t.u = w1 & 0xffff0000; acc[3] += t.f;
    t.u = w2 << 16;        acc[4] += t.f;
    t.u = w2 & 0xffff0000; acc[5] += t.f;
    t.u = w3 << 16;        acc[6] += t.f;
    t.u = w3 & 0xffff0000; acc[7] += t.f;
}

// ===========================================================================
// CSR build: histogram -> 3-kernel multi-block scan -> binning
// ===========================================================================
__global__ __launch_bounds__(256)
void histogram_kernel(const int* __restrict__ dst, int* __restrict__ counts, int E) {
    int i = blockIdx.x * blockDim.x + threadIdx.x;
    if (i < E) atomicAdd(&counts[dst[i]], 1);
}

__global__ __launch_bounds__(256)
void block_sums_kernel(const int* __restrict__ counts, int* __restrict__ partials, int N) {
    int i = blockIdx.x * 256 + threadIdx.x;
    int v = (i < N) ? counts[i] : 0;
    #pragma unroll
    for (int off = 32; off; off >>= 1) v += __shfl_down(v, off);
    __shared__ int ws[4];
    if ((threadIdx.x & 63) == 0) ws[threadIdx.x >> 6] = v;
    __syncthreads();
    if (threadIdx.x == 0) partials[blockIdx.x] = ws[0] + ws[1] + ws[2] + ws[3];
}

__global__ __launch_bounds__(1024)
void scan_partials_kernel(int* __restrict__ partials, int nchunks) {
    __shared__ int s[1024];
    int tid = threadIdx.x;
    int v = (tid < nchunks) ? partials[tid] : 0;
    s[tid] = v;
    __syncthreads();
    for (int off = 1; off < 1024; off <<= 1) {
        int t = (tid >= off) ? s[tid - off] : 0;
        __syncthreads();
        s[tid] += t;
        __syncthreads();
    }
    if (tid < nchunks) partials[tid] = s[tid] - v;   // exclusive
}

__global__ __launch_bounds__(256)
void chunk_scan_kernel(const int* __restrict__ counts, const int* __restrict__ partials,
                       int* __restrict__ offsets, int* __restrict__ cursor, int N) {
    int tid = threadIdx.x;
    int i = blockIdx.x * 256 + tid;
    int v = (i < N) ? counts[i] : 0;
    int lane = tid & 63;
    int incl = v;
    #pragma unroll
    for (int off = 1; off < 64; off <<= 1) {
        int t = __shfl_up(incl, off);
        if (lane >= off) incl += t;
    }
    __shared__ int wsum[4];
    if (lane == 63) wsum[tid >> 6] = incl;
    __syncthreads();
    int w = tid >> 6;
    int add = partials[blockIdx.x];
    for (int k = 0; k < w; ++k) add += wsum[k];
    int excl = add + incl - v;
    if (i < N) { offsets[i] = excl; cursor[i] = excl; }
}

__global__ __launch_bounds__(256)
void binning_kernel(const int* __restrict__ src, const int* __restrict__ dst,
                    int* __restrict__ cursor, int* __restrict__ esrc, int E) {
    int i = blockIdx.x * blockDim.x + threadIdx.x;
    if (i < E) {
        int d = dst[i];
        int pos = atomicAdd(&cursor[d], 1);
        esrc[pos] = src[i];
    }
}

// ===========================================================================
// x fp32 -> bf16 (8 elems/thread)
// ===========================================================================
__global__ __launch_bounds__(256)
void convert_x_kernel(const float* __restrict__ x, unsigned short* __restrict__ xb,
                      long long total8) {
    long long i = (long long)blockIdx.x * blockDim.x + threadIdx.x;
    if (i >= total8) return;
    const float4* p = (const float4*)(x + i * 8);
    float4 a = p[0], b = p[1];
    uint4 o;
    o.x = pack2(a.x, a.y); o.y = pack2(a.z, a.w);
    o.z = pack2(b.x, b.y); o.w = pack2(b.z, b.w);
    *(uint4*)(xb + i * 8) = o;
}

// ===========================================================================
// All four weights -> bf16 transposed [N][K], one launch.
// ===========================================================================
__global__ __launch_bounds__(256)
void convert_weights_kernel(const float* __restrict__ W1_0, const float* __restrict__ W2_0,
                            const float* __restrict__ W1_1, const float* __restrict__ W2_1,
                            unsigned short* __restrict__ wt1_0, unsigned short* __restrict__ wt2_0,
                            unsigned short* __restrict__ wt1_1, unsigned short* __restrict__ wt2_1) {
    int idx = blockIdx.x * blockDim.x + threadIdx.x;
    const int S = FDIM * FDIM;
    const float* W; unsigned short* WT; int local, n, k, Ncols;
    if (idx < S)            { W = W1_0; WT = wt1_0; local = idx;         Ncols = FDIM; }
    else if (idx < 2 * S)   { W = W2_0; WT = wt2_0; local = idx - S;     Ncols = FDIM; }
    else if (idx < 3 * S)   { W = W1_1; WT = wt1_1; local = idx - 2 * S; Ncols = FDIM; }
    else if (idx < 3 * S + FDIM * OUTC)
                            { W = W2_1; WT = wt2_1; local = idx - 3 * S; Ncols = OUTC; }
    else return;
    n = local >> 8;
    k = local & 255;
    WT[local] = f2bf(W[(size_t)k * Ncols + n]);
}

// ===========================================================================
// Gather-aggregate: out[n] = (1+eps)*self[n] + sum xb[src]. One wave per node;
// half-wave per edge (32 lanes x 16B = 512B row), 8 edges per main iter.
// ===========================================================================
template<bool SELF_F32>
__global__ __launch_bounds__(256)
void gather2_kernel(const unsigned short* __restrict__ xb,
                    const float* __restrict__ xf,
                    const int* __restrict__ esrc,
                    const int* __restrict__ offsets, const int* __restrict__ counts,
                    const float* __restrict__ epsp, unsigned short* __restrict__ out,
                    int N) {
    int node = (int)((blockIdx.x * blockDim.x + threadIdx.x) >> 6);
    int lane = threadIdx.x & 63;
    if (node >= N) return;
    int half = lane >> 5;
    int hl   = lane & 31;
    int beg = offsets[node];
    int cnt = counts[node];

    float acc[8] = {0.f, 0.f, 0.f, 0.f, 0.f, 0.f, 0.f, 0.f};

    int e = 0;
    for (; e + 8 <= cnt; e += 8) {
        int s0 = esrc[beg + e + half];
        int s1 = esrc[beg + e + 2 + half];
        int s2 = esrc[beg + e + 4 + half];
        int s3 = esrc[beg + e + 6 + half];
        uint4 v0 = *(const uint4*)(xb + (size_t)s0 * FDIM + hl * 8);
        uint4 v1 = *(const uint4*)(xb + (size_t)s1 * FDIM + hl * 8);
        uint4 v2 = *(const uint4*)(xb + (size_t)s2 * FDIM + hl * 8);
        uint4 v3 = *(const uint4*)(xb + (size_t)s3 * FDIM + hl * 8);
        acc_row(acc, v0);
        acc_row(acc, v1);
        acc_row(acc, v2);
        acc_row(acc, v3);
    }
    for (; e + 2 <= cnt; e += 2) {
        int s0 = esrc[beg + e + half];
        uint4 v0 = *(const uint4*)(xb + (size_t)s0 * FDIM + hl * 8);
        acc_row(acc, v0);
    }
    if (e < cnt && half == 0) {
        int s0 = esrc[beg + e];
        uint4 v0 = *(const uint4*)(xb + (size_t)s0 * FDIM + hl * 8);
        acc_row(acc, v0);
    }

    #pragma unroll
    for (int i = 0; i < 8; ++i) acc[i] += __shfl_xor(acc[i], 32);

    if (half == 0) {
        float scale = 1.0f + *epsp;
        if (SELF_F32) {
            const float4* p = (const float4*)(xf + (size_t)node * FDIM + hl * 8);
            float4 a = p[0], b = p[1];
            acc[0] += scale * a.x; acc[1] += scale * a.y;
            acc[2] += scale * a.z; acc[3] += scale * a.w;
            acc[4] += scale * b.x; acc[5] += scale * b.y;
            acc[6] += scale * b.z; acc[7] += scale * b.w;
        } else {
            uint4 v = *(const uint4*)(xb + (size_t)node * FDIM + hl * 8);
            float sv[8];
            union { unsigned u; float f; } t;
            t.u = v.x << 16;        sv[0] = t.f;
            t.u = v.x & 0xffff0000; sv[1] = t.f;
            t.u = v.y << 16;        sv[2] = t.f;
            t.u = v.y & 0xffff0000; sv[3] = t.f;
            t.u = v.z << 16;        sv[4] = t.f;
            t.u = v.z & 0xffff0000; sv[5] = t.f;
            t.u = v.w << 16;        sv[6] = t.f;
            t.u = v.w & 0xffff0000; sv[7] = t.f;
            #pragma unroll
            for (int i = 0; i < 8; ++i) acc[i] += scale * sv[i];
        }
        uint4 o;
        o.x = pack2(acc[0], acc[1]);
        o.y = pack2(acc[2], acc[3]);
        o.z = pack2(acc[4], acc[5]);
        o.w = pack2(acc[6], acc[7]);
        *(uint4*)(out + (size_t)node * FDIM + hl * 8) = o;
    }
}

// ===========================================================================
// Fused MLP layer: out = f2(relu(A @ W1T^T + b1) @ W2T^T + b2)
//   FINAL=false: f2 = ReLU, out bf16 [M,256]
//   FINAL=true : f2 = log_softmax, out fp32 [M,128]
// One block = 64 rows. A strip staged in LDS once (full K=256); hidden h
// overwrites the same LDS region. B-fragments loaded directly from global
// (weights are L2-resident; all blocks share them). No K-loop barriers.
// 256 threads = 4 waves; wave w owns output cols [64w,64w+64) (stage2 FINAL:
// [32w,32w+32)).
// ===========================================================================
#define LDA 264   // 256 + 8 shorts padding per row

template<bool FINAL>
__global__ __launch_bounds__(256)
void mlp_fused_kernel(const unsigned short* __restrict__ A,    // [M,256] bf16
                      const unsigned short* __restrict__ W1T,  // [256,256] bf16
                      const float* __restrict__ b1,            // [256]
                      const unsigned short* __restrict__ W2T,  // [N2,256] bf16
                      const float* __restrict__ b2,            // [N2]
                      void* __restrict__ Out, int M) {
    __shared__ unsigned short As[64 * LDA];
    __shared__ float sred[64 * 4 * 2];   // FINAL only: per-wave max/sum partials

    int tid  = threadIdx.x;
    int wave = tid >> 6;
    int lane = tid & 63;
    int l15  = lane & 15;
    int quad = lane >> 4;
    int row0 = blockIdx.x * 64;

    // ---- stage A strip (64 x 256), contiguous & coalesced ----
    #pragma unroll
    for (int i = 0; i < 8; ++i) {
        int idx = i * 256 + tid;           // 0..2047 chunks of 8 shorts
        int r = idx >> 5;
        int c = (idx & 31) * 8;
        uint4 v = make_uint4(0u, 0u, 0u, 0u);
        int gr = row0 + r;
        if (gr < M) v = *(const uint4*)(A + (size_t)gr * FDIM + c);
        *(uint4*)(As + r * LDA + c) = v;
    }
    __syncthreads();

    floatx4 zero = {0.f, 0.f, 0.f, 0.f};

    // ---- stage 1: h = relu(A @ W1T^T + b1), wave w -> cols 64w.. ----
    {
        floatx4 acc[4][4];
        #pragma unroll
        for (int i = 0; i < 4; ++i)
            #pragma unroll
            for (int j = 0; j < 4; ++j) acc[i][j] = zero;

        const unsigned short* Wb = W1T + (size_t)(wave * 64) * FDIM;
        bf16x8 bcur[4], bnxt[4];
        #pragma unroll
        for (int j = 0; j < 4; ++j)
            bcur[j] = *(const bf16x8*)(Wb + (size_t)(j * 16 + l15) * FDIM + quad * 8);

        for (int kc = 0; kc < 8; ++kc) {
            int k = kc * 32;
            int kn = (kc < 7) ? k + 32 : k;
            #pragma unroll
            for (int j = 0; j < 4; ++j)
                bnxt[j] = *(const bf16x8*)(Wb + (size_t)(j * 16 + l15) * FDIM + kn + quad * 8);
            bf16x8 af[4];
            #pragma unroll
            for (int i = 0; i < 4; ++i)
                af[i] = *(const bf16x8*)(As + (i * 16 + l15) * LDA + k + quad * 8);
            #pragma unroll
            for (int i = 0; i < 4; ++i)
                #pragma unroll
                for (int j = 0; j < 4; ++j)
                    acc[i][j] = __builtin_amdgcn_mfma_f32_16x16x32_bf16(
                        af[i], bcur[j], acc[i][j], 0, 0, 0);
            #pragma unroll
            for (int j = 0; j < 4; ++j) bcur[j] = bnxt[j];
        }

        __syncthreads();   // all As reads complete before overwrite

        // epilogue: bias + relu, h -> As region (bf16)
        #pragma unroll
        for (int j = 0; j < 4; ++j) {
            int col = wave * 64 + j * 16 + l15;
            float bv = b1[col];
            #pragma unroll
            for (int i = 0; i < 4; ++i) {
                #pragma unroll
                for (int r = 0; r < 4; ++r) {
                    float v = fmaxf(acc[i][j][r] + bv, 0.f);
                    As[(i * 16 + quad * 4 + r) * LDA + col] = f2bf(v);
                }
            }
        }
    }
    __syncthreads();

    // ---- stage 2 ----
    if (!FINAL) {
        floatx4 acc[4][4];
        #pragma unroll
        for (int i = 0; i < 4; ++i)
            #pragma unroll
            for (int j = 0; j < 4; ++j) acc[i][j] = zero;

        const unsigned short* Wb = W2T + (size_t)(wave * 64) * FDIM;
        bf16x8 bcur[4], bnxt[4];
        #pragma unroll
        for (int j = 0; j < 4; ++j)
            bcur[j] = *(const bf16x8*)(Wb + (size_t)(j * 16 + l15) * FDIM + quad * 8);

        for (int kc = 0; kc < 8; ++kc) {
            int k = kc * 32;
            int kn = (kc < 7) ? k + 32 : k;
            #pragma unroll
            for (int j = 0; j < 4; ++j)
                bnxt[j] = *(const bf16x8*)(Wb + (size_t)(j * 16 + l15) * FDIM + kn + quad * 8);
            bf16x8 af[4];
            #pragma unroll
            for (int i = 0; i < 4; ++i)
                af[i] = *(const bf16x8*)(As + (i * 16 + l15) * LDA + k + quad * 8);
            #pragma unroll
            for (int i = 0; i < 4; ++i)
                #pragma unroll
                for (int j = 0; j < 4; ++j)
                    acc[i][j] = __builtin_amdgcn_mfma_f32_16x16x32_bf16(
                        af[i], bcur[j], acc[i][j], 0, 0, 0);
            #pragma unroll
            for (int j = 0; j < 4; ++j) bcur[j] = bnxt[j];
        }

        unsigned short* O = (unsigned short*)Out;
        #pragma unroll
        for (int j = 0; j < 4; ++j) {
            int col = wave * 64 + j * 16 + l15;
            float bv = b2[col];
            #pragma unroll
            for (int i = 0; i < 4; ++i) {
                #pragma unroll
                for (int r = 0; r < 4; ++r) {
                    int grow = row0 + i * 16 + quad * 4 + r;
                    if (grow < M) {
                        float v = fmaxf(acc[i][j][r] + bv, 0.f);
                        O[(size_t)grow * FDIM + col] = f2bf(v);
                    }
                }
            }
        }
    } else {
        // N2 = 128: wave w -> cols [32w, 32w+32)
        floatx4 acc[4][2];
        #pragma unroll
        for (int i = 0; i < 4; ++i)
            #pragma unroll
            for (int j = 0; j < 2; ++j) acc[i][j] = zero;

        const unsigned short* Wb = W2T + (size_t)(wave * 32) * FDIM;
        bf16x8 bcur[2], bnxt[2];
        #pragma unroll
        for (int j = 0; j < 2; ++j)
            bcur[j] = *(const bf16x8*)(Wb + (size_t)(j * 16 + l15) * FDIM + quad * 8);

        for (int kc = 0; kc < 8; ++kc) {
            int k = kc * 32;
            int kn = (kc < 7) ? k + 32 : k;
            #pragma unroll
            for (int j = 0; j < 2; ++j)
                bnxt[j] = *(const bf16x8*)(Wb + (size_t)(j * 16 + l15) * FDIM + kn + quad * 8);
            bf16x8 af[4];
            #pragma unroll
            for (int i = 0; i < 4; ++i)
                af[i] = *(const bf16x8*)(As + (i * 16 + l15) * LDA + k + quad * 8);
            #pragma unroll
            for (int i = 0; i < 4; ++i)
                #pragma unroll
                for (int j = 0; j < 2; ++j)
                    acc[i][j] = __builtin_amdgcn_mfma_f32_16x16x32_bf16(
                        af[i], bcur[j], acc[i][j], 0, 0, 0);
            #pragma unroll
            for (int j = 0; j < 2; ++j) bcur[j] = bnxt[j];
        }

        // bias
        #pragma unroll
        for (int j = 0; j < 2; ++j) {
            float bv = b2[wave * 32 + j * 16 + l15];
            #pragma unroll
            for (int i = 0; i < 4; ++i)
                #pragma unroll
                for (int r = 0; r < 4; ++r) acc[i][j][r] += bv;
        }

        float* smax = sred;
        float* ssum = sred + 256;

        // per-row max: reduce 2 regs, then 16-lane butterfly, partial per wave
        #pragma unroll
        for (int i = 0; i < 4; ++i) {
            #pragma unroll
            for (int r = 0; r < 4; ++r) {
                float m = fmaxf(acc[i][0][r], acc[i][1][r]);
                #pragma unroll
                for (int off = 1; off < 16; off <<= 1) m = fmaxf(m, __shfl_xor(m, off));
                int row = i * 16 + quad * 4 + r;
                if (l15 == 0) smax[row * 4 + wave] = m;
            }
        }
        __syncthreads();

        float Mloc[4][4];
        #pragma unroll
        for (int i = 0; i < 4; ++i) {
            #pragma unroll
            for (int r = 0; r < 4; ++r) {
                int row = i * 16 + quad * 4 + r;
                float Mr = fmaxf(fmaxf(smax[row * 4 + 0], smax[row * 4 + 1]),
                                 fmaxf(smax[row * 4 + 2], smax[row * 4 + 3]));
                Mloc[i][r] = Mr;
                float s = __expf(acc[i][0][r] - Mr) + __expf(acc[i][1][r] - Mr);
                #pragma unroll
                for (int off = 1; off < 16; off <<= 1) s += __shfl_xor(s, off);
                if (l15 == 0) ssum[row * 4 + wave] = s;
            }
        }
        __syncthreads();

        float* O = (float*)Out;
        #pragma unroll
        for (int i = 0; i < 4; ++i) {
            #pragma unroll
            for (int r = 0; r < 4; ++r) {
                int row = i * 16 + quad * 4 + r;
                int grow = row0 + row;
                if (grow < M) {
                    float lse = Mloc[i][r] +
                        __logf(ssum[row * 4 + 0] + ssum[row * 4 + 1] +
                               ssum[row * 4 + 2] + ssum[row * 4 + 3]);
                    #pragma unroll
                    for (int j = 0; j < 2; ++j) {
                        int col = wave * 32 + j * 16 + l15;
                        O[(size_t)grow * OUTC + col] = acc[i][j][r] - lse;
                    }
                }
            }
        }
    }
}

// ===========================================================================
extern "C" void kernel_launch(void* const* d_in, const int* in_sizes, int n_in,
                              void* d_out, int out_size, void* d_ws, size_t ws_size,
                              hipStream_t stream) {
    const float* x    = (const float*)d_in[0];
    const int*   ei   = (const int*)d_in[1];
    const float* eps0 = (const float*)d_in[2];
    const float* W1_0 = (const float*)d_in[3];
    const float* b1_0 = (const float*)d_in[4];
    const float* W2_0 = (const float*)d_in[5];
    const float* b2_0 = (const float*)d_in[6];
    const float* eps1 = (const float*)d_in[7];
    const float* W1_1 = (const float*)d_in[8];
    const float* b1_1 = (const float*)d_in[9];
    const float* W2_1 = (const float*)d_in[10];
    const float* b2_1 = (const float*)d_in[11];
    float* out = (float*)d_out;

    const int N = in_sizes[0] / FDIM;      // 50000
    const int E = in_sizes[1] / 2;         // 800000
    const int* src = ei;
    const int* dst = ei + E;

    size_t buf_elems = (size_t)N * FDIM;
    unsigned short* agg = (unsigned short*)d_ws;
    unsigned short* h2  = agg + buf_elems;
    unsigned short* xb  = h2 + buf_elems;
    unsigned short* wt1_0 = xb + buf_elems;
    unsigned short* wt2_0 = wt1_0 + FDIM * FDIM;
    unsigned short* wt1_1 = wt2_0 + FDIM * FDIM;
    unsigned short* wt2_1 = wt1_1 + FDIM * FDIM;
    int* counts  = (int*)(wt2_1 + FDIM * OUTC);
    int* offsets = counts + N;
    int* cursor  = offsets + N;
    int* esrc    = cursor + N;
    int* partials = esrc + E;

    int eb = (E + 255) / 256;
    int gather_blocks = (N + 3) / 4;
    int nchunks = (N + 255) / 256;
    int mlp_blocks = (N + 63) / 64;

    // ---- CSR build ----
    hipMemsetAsync(counts, 0, (size_t)N * sizeof(int), stream);
    histogram_kernel<<<eb, 256, 0, stream>>>(dst, counts, E);
    block_sums_kernel<<<nchunks, 256, 0, stream>>>(counts, partials, N);
    scan_partials_kernel<<<1, 1024, 0, stream>>>(partials, nchunks);
    chunk_scan_kernel<<<nchunks, 256, 0, stream>>>(counts, partials, offsets, cursor, N);
    binning_kernel<<<eb, 256, 0, stream>>>(src, dst, cursor, esrc, E);

    // ---- converts ----
    long long total8 = (long long)buf_elems / 8;
    convert_x_kernel<<<(int)((total8 + 255) / 256), 256, 0, stream>>>(x, xb, total8);
    int wtot = 3 * FDIM * FDIM + FDIM * OUTC;
    convert_weights_kernel<<<(wtot + 255) / 256, 256, 0, stream>>>(
        W1_0, W2_0, W1_1, W2_1, wt1_0, wt2_0, wt1_1, wt2_1);

    // ---- layer 0 ----
    gather2_kernel<true><<<gather_blocks, 256, 0, stream>>>(
        xb, x, esrc, offsets, counts, eps0, agg, N);
    mlp_fused_kernel<false><<<mlp_blocks, 256, 0, stream>>>(
        agg, wt1_0, b1_0, wt2_0, b2_0, h2, N);

    // ---- layer 1 ----
    gather2_kernel<false><<<gather_blocks, 256, 0, stream>>>(
        h2, nullptr, esrc, offsets, counts, eps1, agg, N);
    mlp_fused_kernel<true><<<mlp_blocks, 256, 0, stream>>>(
        agg, wt1_1, b1_1, wt2_1, b2_1, out, N);
}

// Round 8
// 393.618 us; speedup vs baseline: 14.9331x; 1.0885x over previous
//
#include <hip/hip_runtime.h>
#include <hip/hip_bf16.h>

#define FDIM 256
#define OUTC 128

typedef float floatx4 __attribute__((ext_vector_type(4)));
typedef float floatx2 __attribute__((ext_vector_type(2)));
typedef __bf16 bf16x8 __attribute__((ext_vector_type(8)));

__device__ __forceinline__ unsigned short f2bf(float f) {
    union { float f; unsigned u; } v; v.f = f;
    unsigned r = v.u + 0x7FFF + ((v.u >> 16) & 1);   // RNE
    return (unsigned short)(r >> 16);
}
__device__ __forceinline__ unsigned pack2(float a, float b) {
    return ((unsigned)f2bf(a)) | (((unsigned)f2bf(b)) << 16);
}
// accumulate one 16B chunk (8 bf16) into 4 packed float2 accumulators
__device__ __forceinline__ void acc_row2(floatx2* a, uint4 v) {
    union { unsigned u; float f; } lo, hi;
    lo.u = v.x << 16; hi.u = v.x & 0xffff0000u; a[0] += (floatx2){lo.f, hi.f};
    lo.u = v.y << 16; hi.u = v.y & 0xffff0000u; a[1] += (floatx2){lo.f, hi.f};
    lo.u = v.z << 16; hi.u = v.z & 0xffff0000u; a[2] += (floatx2){lo.f, hi.f};
    lo.u = v.w << 16; hi.u = v.w & 0xffff0000u; a[3] += (floatx2){lo.f, hi.f};
}

// ===========================================================================
// prep kernel: histogram(dst) + convert x->bf16 + convert weights to
// MFMA-fragment-major bf16 layout, one launch (block-range split).
// Fragment-major layout: idx = ((((g*8)+kc)*J + j)*64 + lane)*8 + e
//   lane = quad*16 + l15;  n = g*(16*J) + j*16 + l15;  k = kc*32 + quad*8 + e
// J=4 for 256-col weights, J=2 for the 128-col final weight.
// ===========================================================================
__global__ __launch_bounds__(256)
void prep_kernel(const int* __restrict__ dst, int* __restrict__ counts, int E,
                 const float* __restrict__ x, unsigned short* __restrict__ xb, int total8,
                 const float* __restrict__ W1_0, const float* __restrict__ W2_0,
                 const float* __restrict__ W1_1, const float* __restrict__ W2_1,
                 unsigned short* __restrict__ w1f_0, unsigned short* __restrict__ w2f_0,
                 unsigned short* __restrict__ w1f_1, unsigned short* __restrict__ w2f_1) {
    int gid = blockIdx.x * 256 + threadIdx.x;
    if (gid < E) {
        atomicAdd(&counts[dst[gid]], 1);
        return;
    }
    gid -= E;
    if (gid < total8) {
        const float4* p = (const float4*)(x + (size_t)gid * 8);
        float4 a = p[0], b = p[1];
        uint4 o;
        o.x = pack2(a.x, a.y); o.y = pack2(a.z, a.w);
        o.z = pack2(b.x, b.y); o.w = pack2(b.z, b.w);
        *(uint4*)(xb + (size_t)gid * 8) = o;
        return;
    }
    gid -= total8;
    const int S = FDIM * FDIM;   // 65536
    const float* W; unsigned short* WF; int local, J, Ncols;
    if (gid < S)          { W = W1_0; WF = w1f_0; local = gid;         J = 4; Ncols = FDIM; }
    else if (gid < 2 * S) { W = W2_0; WF = w2f_0; local = gid - S;     J = 4; Ncols = FDIM; }
    else if (gid < 3 * S) { W = W1_1; WF = w1f_1; local = gid - 2 * S; J = 4; Ncols = FDIM; }
    else if (gid < 3 * S + FDIM * OUTC)
                          { W = W2_1; WF = w2f_1; local = gid - 3 * S; J = 2; Ncols = OUTC; }
    else return;
    int e    = local & 7;
    int lane = (local >> 3) & 63;
    int l15  = lane & 15;
    int quad = lane >> 4;
    int rest = local >> 9;
    int j  = rest % J;  rest /= J;
    int kc = rest & 7;
    int g  = rest >> 3;
    int n = g * (16 * J) + j * 16 + l15;
    int k = kc * 32 + quad * 8 + e;
    WF[local] = f2bf(W[(size_t)k * Ncols + n]);
}

// ===========================================================================
// multi-block scan: block sums -> 1-block scan -> per-chunk scan
// ===========================================================================
__global__ __launch_bounds__(256)
void block_sums_kernel(const int* __restrict__ counts, int* __restrict__ partials, int N) {
    int i = blockIdx.x * 256 + threadIdx.x;
    int v = (i < N) ? counts[i] : 0;
    #pragma unroll
    for (int off = 32; off; off >>= 1) v += __shfl_down(v, off);
    __shared__ int ws[4];
    if ((threadIdx.x & 63) == 0) ws[threadIdx.x >> 6] = v;
    __syncthreads();
    if (threadIdx.x == 0) partials[blockIdx.x] = ws[0] + ws[1] + ws[2] + ws[3];
}

__global__ __launch_bounds__(1024)
void scan_partials_kernel(int* __restrict__ partials, int nchunks) {
    __shared__ int s[1024];
    int tid = threadIdx.x;
    int v = (tid < nchunks) ? partials[tid] : 0;
    s[tid] = v;
    __syncthreads();
    for (int off = 1; off < 1024; off <<= 1) {
        int t = (tid >= off) ? s[tid - off] : 0;
        __syncthreads();
        s[tid] += t;
        __syncthreads();
    }
    if (tid < nchunks) partials[tid] = s[tid] - v;   // exclusive
}

__global__ __launch_bounds__(256)
void chunk_scan_kernel(const int* __restrict__ counts, const int* __restrict__ partials,
                       int* __restrict__ offsets, int* __restrict__ cursor, int N) {
    int tid = threadIdx.x;
    int i = blockIdx.x * 256 + tid;
    int v = (i < N) ? counts[i] : 0;
    int lane = tid & 63;
    int incl = v;
    #pragma unroll
    for (int off = 1; off < 64; off <<= 1) {
        int t = __shfl_up(incl, off);
        if (lane >= off) incl += t;
    }
    __shared__ int wsum[4];
    if (lane == 63) wsum[tid >> 6] = incl;
    __syncthreads();
    int w = tid >> 6;
    int add = partials[blockIdx.x];
    for (int k = 0; k < w; ++k) add += wsum[k];
    int excl = add + incl - v;
    if (i < N) { offsets[i] = excl; cursor[i] = excl; }
}

__global__ __launch_bounds__(256)
void binning_kernel(const int* __restrict__ src, const int* __restrict__ dst,
                    int* __restrict__ cursor, int* __restrict__ esrc, int E) {
    int i = blockIdx.x * blockDim.x + threadIdx.x;
    if (i < E) {
        int d = dst[i];
        int pos = atomicAdd(&cursor[d], 1);
        esrc[pos] = src[i];
    }
}

// ===========================================================================
// Gather-aggregate: out[n] = (1+eps)*self[n] + sum xb[src]. One wave per node;
// half-wave per edge (32 lanes x 16B = 512B row). Main loop: 8 rows in
// flight per half-wave (16 edges/wave/iter). Packed float2 accumulate.
// ===========================================================================
template<bool SELF_F32>
__global__ __launch_bounds__(256)
void gather2_kernel(const unsigned short* __restrict__ xb,
                    const float* __restrict__ xf,
                    const int* __restrict__ esrc,
                    const int* __restrict__ offsets, const int* __restrict__ counts,
                    const float* __restrict__ epsp, unsigned short* __restrict__ out,
                    int N) {
    int node = (int)((blockIdx.x * blockDim.x + threadIdx.x) >> 6);
    int lane = threadIdx.x & 63;
    if (node >= N) return;
    int half = lane >> 5;
    int hl   = lane & 31;
    int beg = offsets[node];
    int cnt = counts[node];

    floatx2 acc[4];
    acc[0] = (floatx2){0.f, 0.f}; acc[1] = (floatx2){0.f, 0.f};
    acc[2] = (floatx2){0.f, 0.f}; acc[3] = (floatx2){0.f, 0.f};

    int e = 0;
    for (; e + 16 <= cnt; e += 16) {
        int s[8];
        #pragma unroll
        for (int k = 0; k < 8; ++k) s[k] = esrc[beg + e + 2 * k + half];
        uint4 v[8];
        #pragma unroll
        for (int k = 0; k < 8; ++k)
            v[k] = *(const uint4*)(xb + (size_t)s[k] * FDIM + hl * 8);
        #pragma unroll
        for (int k = 0; k < 8; ++k) acc_row2(acc, v[k]);
    }
    for (; e + 4 <= cnt; e += 4) {
        int s0 = esrc[beg + e + half];
        int s1 = esrc[beg + e + 2 + half];
        uint4 v0 = *(const uint4*)(xb + (size_t)s0 * FDIM + hl * 8);
        uint4 v1 = *(const uint4*)(xb + (size_t)s1 * FDIM + hl * 8);
        acc_row2(acc, v0);
        acc_row2(acc, v1);
    }
    if (e + 2 <= cnt) {
        int s0 = esrc[beg + e + half];
        uint4 v0 = *(const uint4*)(xb + (size_t)s0 * FDIM + hl * 8);
        acc_row2(acc, v0);
        e += 2;
    }
    if (e < cnt && half == 0) {
        int s0 = esrc[beg + e];
        uint4 v0 = *(const uint4*)(xb + (size_t)s0 * FDIM + hl * 8);
        acc_row2(acc, v0);
    }

    // combine the two half-wave partial sums
    float a8[8];
    #pragma unroll
    for (int i = 0; i < 4; ++i) { a8[2 * i] = acc[i][0]; a8[2 * i + 1] = acc[i][1]; }
    #pragma unroll
    for (int i = 0; i < 8; ++i) a8[i] += __shfl_xor(a8[i], 32);

    if (half == 0) {
        float scale = 1.0f + *epsp;
        if (SELF_F32) {
            const float4* p = (const float4*)(xf + (size_t)node * FDIM + hl * 8);
            float4 a = p[0], b = p[1];
            a8[0] += scale * a.x; a8[1] += scale * a.y;
            a8[2] += scale * a.z; a8[3] += scale * a.w;
            a8[4] += scale * b.x; a8[5] += scale * b.y;
            a8[6] += scale * b.z; a8[7] += scale * b.w;
        } else {
            uint4 v = *(const uint4*)(xb + (size_t)node * FDIM + hl * 8);
            union { unsigned u; float f; } t;
            t.u = v.x << 16;         a8[0] += scale * t.f;
            t.u = v.x & 0xffff0000u; a8[1] += scale * t.f;
            t.u = v.y << 16;         a8[2] += scale * t.f;
            t.u = v.y & 0xffff0000u; a8[3] += scale * t.f;
            t.u = v.z << 16;         a8[4] += scale * t.f;
            t.u = v.z & 0xffff0000u; a8[5] += scale * t.f;
            t.u = v.w << 16;         a8[6] += scale * t.f;
            t.u = v.w & 0xffff0000u; a8[7] += scale * t.f;
        }
        uint4 o;
        o.x = pack2(a8[0], a8[1]);
        o.y = pack2(a8[2], a8[3]);
        o.z = pack2(a8[4], a8[5]);
        o.w = pack2(a8[6], a8[7]);
        *(uint4*)(out + (size_t)node * FDIM + hl * 8) = o;
    }
}

// ===========================================================================
// Fused MLP layer: out = f2(relu(A @ W1^T + b1) @ W2^T + b2)
// Weights in fragment-major layout (see prep_kernel): wave B-loads are 1KB
// contiguous. One block = 64 rows; A strip in LDS; h overwrites A region.
// ===========================================================================
#define LDA 264   // 256 + 8 shorts padding per row

template<bool FINAL>
__global__ __launch_bounds__(256)
void mlp_fused_kernel(const unsigned short* __restrict__ A,    // [M,256] bf16
                      const unsigned short* __restrict__ W1F,  // frag-major
                      const float* __restrict__ b1,
                      const unsigned short* __restrict__ W2F,  // frag-major
                      const float* __restrict__ b2,
                      void* __restrict__ Out, int M) {
    __shared__ unsigned short As[64 * LDA];
    __shared__ float sred[64 * 4 * 2];

    int tid  = threadIdx.x;
    int wave = tid >> 6;
    int lane = tid & 63;
    int l15  = lane & 15;
    int quad = lane >> 4;
    int row0 = blockIdx.x * 64;

    // ---- stage A strip (64 x 256) ----
    #pragma unroll
    for (int i = 0; i < 8; ++i) {
        int idx = i * 256 + tid;
        int r = idx >> 5;
        int c = (idx & 31) * 8;
        uint4 v = make_uint4(0u, 0u, 0u, 0u);
        int gr = row0 + r;
        if (gr < M) v = *(const uint4*)(A + (size_t)gr * FDIM + c);
        *(uint4*)(As + r * LDA + c) = v;
    }
    __syncthreads();

    floatx4 zero = {0.f, 0.f, 0.f, 0.f};

    // ---- stage 1: h = relu(A @ W1 + b1), wave w -> cols [64w,64w+64) ----
    {
        floatx4 acc[4][4];
        #pragma unroll
        for (int i = 0; i < 4; ++i)
            #pragma unroll
            for (int j = 0; j < 4; ++j) acc[i][j] = zero;

        const unsigned short* Wb = W1F + (size_t)wave * 16384;  // 8kc*4j*64lane*8
        bf16x8 bcur[4], bnxt[4];
        #pragma unroll
        for (int j = 0; j < 4; ++j)
            bcur[j] = *(const bf16x8*)(Wb + j * 512 + lane * 8);

        for (int kc = 0; kc < 8; ++kc) {
            const unsigned short* Wn = Wb + ((kc < 7) ? (kc + 1) : kc) * 2048;
            #pragma unroll
            for (int j = 0; j < 4; ++j)
                bnxt[j] = *(const bf16x8*)(Wn + j * 512 + lane * 8);
            bf16x8 af[4];
            int k = kc * 32;
            #pragma unroll
            for (int i = 0; i < 4; ++i)
                af[i] = *(const bf16x8*)(As + (i * 16 + l15) * LDA + k + quad * 8);
            #pragma unroll
            for (int i = 0; i < 4; ++i)
                #pragma unroll
                for (int j = 0; j < 4; ++j)
                    acc[i][j] = __builtin_amdgcn_mfma_f32_16x16x32_bf16(
                        af[i], bcur[j], acc[i][j], 0, 0, 0);
            #pragma unroll
            for (int j = 0; j < 4; ++j) bcur[j] = bnxt[j];
        }

        __syncthreads();   // all As reads complete before overwrite

        #pragma unroll
        for (int j = 0; j < 4; ++j) {
            int col = wave * 64 + j * 16 + l15;
            float bv = b1[col];
            #pragma unroll
            for (int i = 0; i < 4; ++i) {
                #pragma unroll
                for (int r = 0; r < 4; ++r) {
                    float v = fmaxf(acc[i][j][r] + bv, 0.f);
                    As[(i * 16 + quad * 4 + r) * LDA + col] = f2bf(v);
                }
            }
        }
    }
    __syncthreads();

    // ---- stage 2 ----
    if (!FINAL) {
        floatx4 acc[4][4];
        #pragma unroll
        for (int i = 0; i < 4; ++i)
            #pragma unroll
            for (int j = 0; j < 4; ++j) acc[i][j] = zero;

        const unsigned short* Wb = W2F + (size_t)wave * 16384;
        bf16x8 bcur[4], bnxt[4];
        #pragma unroll
        for (int j = 0; j < 4; ++j)
            bcur[j] = *(const bf16x8*)(Wb + j * 512 + lane * 8);

        for (int kc = 0; kc < 8; ++kc) {
            const unsigned short* Wn = Wb + ((kc < 7) ? (kc + 1) : kc) * 2048;
            #pragma unroll
            for (int j = 0; j < 4; ++j)
                bnxt[j] = *(const bf16x8*)(Wn + j * 512 + lane * 8);
            bf16x8 af[4];
            int k = kc * 32;
            #pragma unroll
            for (int i = 0; i < 4; ++i)
                af[i] = *(const bf16x8*)(As + (i * 16 + l15) * LDA + k + quad * 8);
            #pragma unroll
            for (int i = 0; i < 4; ++i)
                #pragma unroll
                for (int j = 0; j < 4; ++j)
                    acc[i][j] = __builtin_amdgcn_mfma_f32_16x16x32_bf16(
                        af[i], bcur[j], acc[i][j], 0, 0, 0);
            #pragma unroll
            for (int j = 0; j < 4; ++j) bcur[j] = bnxt[j];
        }

        unsigned short* O = (unsigned short*)Out;
        #pragma unroll
        for (int j = 0; j < 4; ++j) {
            int col = wave * 64 + j * 16 + l15;
            float bv = b2[col];
            #pragma unroll
            for (int i = 0; i < 4; ++i) {
                #pragma unroll
                for (int r = 0; r < 4; ++r) {
                    int grow = row0 + i * 16 + quad * 4 + r;
                    if (grow < M) {
                        float v = fmaxf(acc[i][j][r] + bv, 0.f);
                        O[(size_t)grow * FDIM + col] = f2bf(v);
                    }
                }
            }
        }
    } else {
        // N2 = 128: wave w -> cols [32w, 32w+32), J=2 fragment groups
        floatx4 acc[4][2];
        #pragma unroll
        for (int i = 0; i < 4; ++i)
            #pragma unroll
            for (int j = 0; j < 2; ++j) acc[i][j] = zero;

        const unsigned short* Wb = W2F + (size_t)wave * 8192;   // 8kc*2j*64*8
        bf16x8 bcur[2], bnxt[2];
        #pragma unroll
        for (int j = 0; j < 2; ++j)
            bcur[j] = *(const bf16x8*)(Wb + j * 512 + lane * 8);

        for (int kc = 0; kc < 8; ++kc) {
            const unsigned short* Wn = Wb + ((kc < 7) ? (kc + 1) : kc) * 1024;
            #pragma unroll
            for (int j = 0; j < 2; ++j)
                bnxt[j] = *(const bf16x8*)(Wn + j * 512 + lane * 8);
            bf16x8 af[4];
            int k = kc * 32;
            #pragma unroll
            for (int i = 0; i < 4; ++i)
                af[i] = *(const bf16x8*)(As + (i * 16 + l15) * LDA + k + quad * 8);
            #pragma unroll
            for (int i = 0; i < 4; ++i)
                #pragma unroll
                for (int j = 0; j < 2; ++j)
                    acc[i][j] = __builtin_amdgcn_mfma_f32_16x16x32_bf16(
                        af[i], bcur[j], acc[i][j], 0, 0, 0);
            #pragma unroll
            for (int j = 0; j < 2; ++j) bcur[j] = bnxt[j];
        }

        #pragma unroll
        for (int j = 0; j < 2; ++j) {
            float bv = b2[wave * 32 + j * 16 + l15];
            #pragma unroll
            for (int i = 0; i < 4; ++i)
                #pragma unroll
                for (int r = 0; r < 4; ++r) acc[i][j][r] += bv;
        }

        float* smax = sred;
        float* ssum = sred + 256;

        #pragma unroll
        for (int i = 0; i < 4; ++i) {
            #pragma unroll
            for (int r = 0; r < 4; ++r) {
                float m = fmaxf(acc[i][0][r], acc[i][1][r]);
                #pragma unroll
                for (int off = 1; off < 16; off <<= 1) m = fmaxf(m, __shfl_xor(m, off));
                int row = i * 16 + quad * 4 + r;
                if (l15 == 0) smax[row * 4 + wave] = m;
            }
        }
        __syncthreads();

        float Mloc[4][4];
        #pragma unroll
        for (int i = 0; i < 4; ++i) {
            #pragma unroll
            for (int r = 0; r < 4; ++r) {
                int row = i * 16 + quad * 4 + r;
                float Mr = fmaxf(fmaxf(smax[row * 4 + 0], smax[row * 4 + 1]),
                                 fmaxf(smax[row * 4 + 2], smax[row * 4 + 3]));
                Mloc[i][r] = Mr;
                float s = __expf(acc[i][0][r] - Mr) + __expf(acc[i][1][r] - Mr);
                #pragma unroll
                for (int off = 1; off < 16; off <<= 1) s += __shfl_xor(s, off);
                if (l15 == 0) ssum[row * 4 + wave] = s;
            }
        }
        __syncthreads();

        float* O = (float*)Out;
        #pragma unroll
        for (int i = 0; i < 4; ++i) {
            #pragma unroll
            for (int r = 0; r < 4; ++r) {
                int row = i * 16 + quad * 4 + r;
                int grow = row0 + row;
                if (grow < M) {
                    float lse = Mloc[i][r] +
                        __logf(ssum[row * 4 + 0] + ssum[row * 4 + 1] +
                               ssum[row * 4 + 2] + ssum[row * 4 + 3]);
                    #pragma unroll
                    for (int j = 0; j < 2; ++j) {
                        int col = wave * 32 + j * 16 + l15;
                        O[(size_t)grow * OUTC + col] = acc[i][j][r] - lse;
                    }
                }
            }
        }
    }
}

// ===========================================================================
extern "C" void kernel_launch(void* const* d_in, const int* in_sizes, int n_in,
                              void* d_out, int out_size, void* d_ws, size_t ws_size,
                              hipStream_t stream) {
    const float* x    = (const float*)d_in[0];
    const int*   ei   = (const int*)d_in[1];
    const float* eps0 = (const float*)d_in[2];
    const float* W1_0 = (const float*)d_in[3];
    const float* b1_0 = (const float*)d_in[4];
    const float* W2_0 = (const float*)d_in[5];
    const float* b2_0 = (const float*)d_in[6];
    const float* eps1 = (const float*)d_in[7];
    const float* W1_1 = (const float*)d_in[8];
    const float* b1_1 = (const float*)d_in[9];
    const float* W2_1 = (const float*)d_in[10];
    const float* b2_1 = (const float*)d_in[11];
    float* out = (float*)d_out;

    const int N = in_sizes[0] / FDIM;      // 50000
    const int E = in_sizes[1] / 2;         // 800000
    const int* src = ei;
    const int* dst = ei + E;

    size_t buf_elems = (size_t)N * FDIM;
    unsigned short* agg = (unsigned short*)d_ws;
    unsigned short* h2  = agg + buf_elems;
    unsigned short* xb  = h2 + buf_elems;
    unsigned short* w1f_0 = xb + buf_elems;
    unsigned short* w2f_0 = w1f_0 + FDIM * FDIM;
    unsigned short* w1f_1 = w2f_0 + FDIM * FDIM;
    unsigned short* w2f_1 = w1f_1 + FDIM * FDIM;
    int* counts  = (int*)(w2f_1 + FDIM * OUTC);
    int* offsets = counts + N;
    int* cursor  = offsets + N;
    int* esrc    = cursor + N;
    int* partials = esrc + E;

    int eb = (E + 255) / 256;
    int gather_blocks = (N + 3) / 4;
    int nchunks = (N + 255) / 256;
    int mlp_blocks = (N + 63) / 64;
    int total8 = (int)(buf_elems / 8);
    int wtot = 3 * FDIM * FDIM + FDIM * OUTC;
    int prep_threads = E + total8 + wtot;

    // ---- CSR build + converts ----
    hipMemsetAsync(counts, 0, (size_t)N * sizeof(int), stream);
    prep_kernel<<<(prep_threads + 255) / 256, 256, 0, stream>>>(
        dst, counts, E, x, xb, total8,
        W1_0, W2_0, W1_1, W2_1, w1f_0, w2f_0, w1f_1, w2f_1);
    block_sums_kernel<<<nchunks, 256, 0, stream>>>(counts, partials, N);
    scan_partials_kernel<<<1, 1024, 0, stream>>>(partials, nchunks);
    chunk_scan_kernel<<<nchunks, 256, 0, stream>>>(counts, partials, offsets, cursor, N);
    binning_kernel<<<eb, 256, 0, stream>>>(src, dst, cursor, esrc, E);

    // ---- layer 0 ----
    gather2_kernel<true><<<gather_blocks, 256, 0, stream>>>(
        xb, x, esrc, offsets, counts, eps0, agg, N);
    mlp_fused_kernel<false><<<mlp_blocks, 256, 0, stream>>>(
        agg, w1f_0, b1_0, w2f_0, b2_0, h2, N);

    // ---- layer 1 ----
    gather2_kernel<false><<<gather_blocks, 256, 0, stream>>>(
        h2, nullptr, esrc, offsets, counts, eps1, agg, N);
    mlp_fused_kernel<true><<<mlp_blocks, 256, 0, stream>>>(
        agg, w1f_1, b1_1, w2f_1, b2_1, out, N);
}